// Round 6
// baseline (98.452 us; speedup 1.0000x reference)
//
#include <hip/hip_runtime.h>
#include <math.h>

#define NROWS 2048
#define HDIM 768
#define DDIM 128
#define FEAT 512
#define DCAP 2048
#define TSLOTS 8192
#define NJS 64

typedef __attribute__((ext_vector_type(8))) short bf16x8;
typedef __attribute__((ext_vector_type(4))) float f32x4;

// Online logsumexp-style merge: state (m, n, d) <- merge with (m2, n2, d2).
__device__ __forceinline__ void mergeState(float& m, float& n, float& d,
                                           float m2, float n2, float d2) {
  float M = fmaxf(m, m2);
  float s1 = (m >= M) ? 1.0f : __expf(m - M);
  float s2 = (m2 >= M) ? 1.0f : __expf(m2 - M);
  n = n * s1 + n2 * s2;
  d = d * s1 + d2 * s2;
  m = M;
}

__device__ __forceinline__ unsigned short bfhi(float x) {
  unsigned int u = __float_as_uint(x);
  return (unsigned short)((u + 0x7fffu + ((u >> 16) & 1u)) >> 16);
}
__device__ __forceinline__ float bf2f(unsigned short h) {
  return __uint_as_float(((unsigned int)h) << 16);
}

__device__ __forceinline__ void gload16(const void* g, void* l) {
  __builtin_amdgcn_global_load_lds(
      (const __attribute__((address_space(1))) void*)g,
      (__attribute__((address_space(3))) void*)l, 16, 0, 0);
}

// ---------------------------------------------------------------------------
// k0_prep: (a) Ehi/Elo = bf16-split of relu(E); (b) Wthi/Wtlo = bf16-split of
// [Wmu|Wsg] transposed to [256 cols][768 k]; (c) clear hash table/flags.
// ---------------------------------------------------------------------------
__global__ __launch_bounds__(256) void k0_prep(
    const float* __restrict__ E, const float* __restrict__ Wmu,
    const float* __restrict__ Wsg,
    unsigned short* __restrict__ Ehi, unsigned short* __restrict__ Elo,
    unsigned short* __restrict__ Wthi, unsigned short* __restrict__ Wtlo,
    unsigned long long* __restrict__ tab, int* __restrict__ rowflag,
    int* __restrict__ dupcnt)
{
  const int bid = blockIdx.x, t = threadIdx.x;
  if (bid < 768) {
    const int base = bid * 2048 + t * 8;
    float4 v0 = *reinterpret_cast<const float4*>(E + base);
    float4 v1 = *reinterpret_cast<const float4*>(E + base + 4);
    const float v[8] = {v0.x, v0.y, v0.z, v0.w, v1.x, v1.y, v1.z, v1.w};
    unsigned short h[8], l[8];
    #pragma unroll
    for (int i = 0; i < 8; ++i) {
      float f = fmaxf(v[i], 0.f);
      h[i] = bfhi(f);
      l[i] = bfhi(f - bf2f(h[i]));
    }
    *reinterpret_cast<ushort4*>(Ehi + base)     = make_ushort4(h[0], h[1], h[2], h[3]);
    *reinterpret_cast<ushort4*>(Ehi + base + 4) = make_ushort4(h[4], h[5], h[6], h[7]);
    *reinterpret_cast<ushort4*>(Elo + base)     = make_ushort4(l[0], l[1], l[2], l[3]);
    *reinterpret_cast<ushort4*>(Elo + base + 4) = make_ushort4(l[4], l[5], l[6], l[7]);
  } else if (bid < 864) {
    const int tid = (bid - 768) * 256 + t;          // 0..24575
    const int c = tid / 96, kc = (tid % 96) * 8;
    unsigned short h[8], l[8];
    #pragma unroll
    for (int j = 0; j < 8; ++j) {
      float w = (c < 128) ? Wmu[(size_t)(kc + j) * DDIM + c]
                          : Wsg[(size_t)(kc + j) * DDIM + (c - 128)];
      h[j] = bfhi(w);
      l[j] = bfhi(w - bf2f(h[j]));
    }
    const size_t o = (size_t)c * HDIM + kc;
    *reinterpret_cast<ushort4*>(Wthi + o)     = make_ushort4(h[0], h[1], h[2], h[3]);
    *reinterpret_cast<ushort4*>(Wthi + o + 4) = make_ushort4(h[4], h[5], h[6], h[7]);
    *reinterpret_cast<ushort4*>(Wtlo + o)     = make_ushort4(l[0], l[1], l[2], l[3]);
    *reinterpret_cast<ushort4*>(Wtlo + o + 4) = make_ushort4(l[4], l[5], l[6], l[7]);
  } else if (bid < 872) {
    const int i4 = (bid - 864) * 1024 + t * 4;
    #pragma unroll
    for (int k = 0; k < 4; ++k) tab[i4 + k] = 0ULL;
    rowflag[(bid - 864) * 256 + t] = 0;
  } else {
    if (t == 0) dupcnt[0] = 0;
  }
}

// ---------------------------------------------------------------------------
// k1m: split-K MFMA projection GEMM. C[2048][256] partials over 4 K-splits.
// Block: M-tile 64, N-tile 128, K-split 192. 256 threads (2x2 waves).
// dbuf LDS (2 x 24 KB), pipelined with counted vmcnt(6).
// ---------------------------------------------------------------------------
__global__ __launch_bounds__(256) void k1m(
    const unsigned short* __restrict__ Ehi, const unsigned short* __restrict__ Elo,
    const unsigned short* __restrict__ Wthi, const unsigned short* __restrict__ Wtlo,
    float* __restrict__ Cpart)
{
  __shared__ unsigned short lds[24576];   // 48 KB = 2 buf x 12288
  const int t = threadIdx.x;
  const int bid = blockIdx.x;
  const int mt = bid & 31, nt = (bid >> 5) & 1, ks = bid >> 6;
  const int i0 = mt * 64, n0 = nt * 128, kbase = ks * 192;

  const unsigned short* gF[6];
  size_t goff[6];
  int lpb[6];
  #pragma unroll
  for (int rr = 0; rr < 6; ++rr) {
    if (rr < 2) {
      const int s = t, gq = s >> 6, row = s & 63;
      gF[rr] = rr ? Elo : Ehi;
      goff[rr] = (size_t)(i0 + row) * HDIM + kbase + gq * 8;
      lpb[rr] = rr * 2048 + (s & ~63) * 8;
    } else {
      const int s = (rr & 1) * 256 + t, gq = s >> 7, row = s & 127;
      gF[rr] = (rr >= 4) ? Wtlo : Wthi;
      goff[rr] = (size_t)(n0 + row) * HDIM + kbase + gq * 8;
      lpb[rr] = (rr >= 4 ? 8192 : 4096) + (s & ~63) * 8;
    }
  }

  f32x4 acc[2][4];
  #pragma unroll
  for (int a = 0; a < 2; ++a)
    #pragma unroll
    for (int b = 0; b < 4; ++b) {
      acc[a][b][0] = 0.f; acc[a][b][1] = 0.f; acc[a][b][2] = 0.f; acc[a][b][3] = 0.f;
    }

  const int wid = t >> 6, lane = t & 63;
  const int wr = wid >> 1, wc = wid & 1;
  const int gq = lane >> 4, c0 = lane & 15;

  auto stage = [&](int it, int buf) {
    unsigned short* lb = lds + buf * 12288;
    #pragma unroll
    for (int rr = 0; rr < 6; ++rr)
      gload16(gF[rr] + goff[rr] + it * 32, lb + lpb[rr]);
  };

  stage(0, 0);
  __syncthreads();

  for (int it = 0; it < 6; ++it) {
    if (it < 5) {
      stage(it + 1, (it + 1) & 1);
      asm volatile("s_waitcnt vmcnt(6)" ::: "memory");
    } else {
      asm volatile("s_waitcnt vmcnt(0)" ::: "memory");
    }
    __builtin_amdgcn_s_barrier();
    {
      const unsigned short* lb = lds + (it & 1) * 12288;
      bf16x8 ah[2], al[2], bh[4], bl[4];
      #pragma unroll
      for (int fa = 0; fa < 2; ++fa) {
        const int ia = gq * 512 + (wr * 32 + fa * 16 + c0) * 8;
        ah[fa] = *reinterpret_cast<const bf16x8*>(lb + ia);
        al[fa] = *reinterpret_cast<const bf16x8*>(lb + 2048 + ia);
      }
      #pragma unroll
      for (int fb = 0; fb < 4; ++fb) {
        const int ib = gq * 1024 + (wc * 64 + fb * 16 + c0) * 8;
        bh[fb] = *reinterpret_cast<const bf16x8*>(lb + 4096 + ib);
        bl[fb] = *reinterpret_cast<const bf16x8*>(lb + 8192 + ib);
      }
      #pragma unroll
      for (int fa = 0; fa < 2; ++fa)
        #pragma unroll
        for (int fb = 0; fb < 4; ++fb) {
          acc[fa][fb] = __builtin_amdgcn_mfma_f32_16x16x32_bf16(ah[fa], bh[fb], acc[fa][fb], 0, 0, 0);
          acc[fa][fb] = __builtin_amdgcn_mfma_f32_16x16x32_bf16(ah[fa], bl[fb], acc[fa][fb], 0, 0, 0);
          acc[fa][fb] = __builtin_amdgcn_mfma_f32_16x16x32_bf16(al[fa], bh[fb], acc[fa][fb], 0, 0, 0);
        }
    }
    __builtin_amdgcn_s_barrier();
  }

  #pragma unroll
  for (int fa = 0; fa < 2; ++fa)
    #pragma unroll
    for (int fb = 0; fb < 4; ++fb)
      #pragma unroll
      for (int r = 0; r < 4; ++r) {
        const int row = i0 + wr * 32 + fa * 16 + gq * 4 + r;
        const int col = n0 + wc * 64 + fb * 16 + c0;
        Cpart[((size_t)ks * NROWS + row) * 256 + col] = acc[fa][fb][r];
      }
}

// ---------------------------------------------------------------------------
// k1e: reduce 4 K-split partials -> mu/sigma -> features Fhi/Flo, q, and
// full-mu-vector duplicate hash (rowflag/duplist). Block = 4 rows.
// ---------------------------------------------------------------------------
__global__ __launch_bounds__(256) void k1e(
    const float* __restrict__ Cpart, const float* __restrict__ bmu,
    const float* __restrict__ bsg,
    unsigned short* __restrict__ Fhi, unsigned short* __restrict__ Flo,
    float* __restrict__ qout, unsigned long long* __restrict__ tab,
    int* __restrict__ rowflag, int* __restrict__ dupcnt,
    int2* __restrict__ duplist)
{
  __shared__ float sigL[4][DDIM];
  const int t = threadIdx.x;
  const int row = t >> 6, cg = t & 63, c4 = cg * 4;
  const int mat = c4 >> 7, colm = c4 & 127;
  const int rg = blockIdx.x * 4 + row;

  float v[4];
  {
    float4 s0 = *reinterpret_cast<const float4*>(&Cpart[((size_t)0 * NROWS + rg) * 256 + c4]);
    float4 s1 = *reinterpret_cast<const float4*>(&Cpart[((size_t)1 * NROWS + rg) * 256 + c4]);
    float4 s2 = *reinterpret_cast<const float4*>(&Cpart[((size_t)2 * NROWS + rg) * 256 + c4]);
    float4 s3 = *reinterpret_cast<const float4*>(&Cpart[((size_t)3 * NROWS + rg) * 256 + c4]);
    v[0] = ((s0.x + s1.x) + s2.x) + s3.x;
    v[1] = ((s0.y + s1.y) + s2.y) + s3.y;
    v[2] = ((s0.z + s1.z) + s2.z) + s3.z;
    v[3] = ((s0.w + s1.w) + s2.w) + s3.w;
  }

  if (mat == 1) {
    #pragma unroll
    for (int c = 0; c < 4; ++c) {
      float z = v[c] + bsg[colm + c];
      float s = (z > 0.f ? z + 1.0f : __expf(z)) + 1e-14f;
      sigL[row][colm + c] = s;
    }
  }
  __syncthreads();

  float q = 0.f;
  unsigned int hx = 0u, hs = 0u;
  if (mat == 0) {
    float f1[4], f2[4], f3[4], f4[4];
    #pragma unroll
    for (int c = 0; c < 4; ++c) {
      float mu = v[c] + bmu[colm + c];
      float s  = sigL[row][colm + c];
      float inv = 1.0f / s;
      f1[c] = inv;
      f2[c] = s + mu * mu;
      f3[c] = -2.0f * mu * inv;
      f4[c] = mu;
      q += mu * mu * inv;
      unsigned int b = __float_as_uint(mu);
      if (b == 0x80000000u) b = 0u;
      unsigned int hm = (b ^ ((unsigned int)(colm + c) * 0x9E3779B9u)) * 0x85EBCA6Bu;
      hm ^= hm >> 13;
      hx ^= hm;
      hs += hm * 0xC2B2AE35u;
    }
    const float* blocks[4] = {f1, f2, f3, f4};
    #pragma unroll
    for (int b = 0; b < 4; ++b) {
      const float* vv = blocks[b];
      unsigned short h[4], l[4];
      #pragma unroll
      for (int c = 0; c < 4; ++c) {
        h[c] = bfhi(vv[c]);
        l[c] = bfhi(vv[c] - bf2f(h[c]));
      }
      size_t off = (size_t)rg * FEAT + b * 128 + colm;
      *reinterpret_cast<ushort4*>(&Fhi[off]) = make_ushort4(h[0], h[1], h[2], h[3]);
      *reinterpret_cast<ushort4*>(&Flo[off]) = make_ushort4(l[0], l[1], l[2], l[3]);
    }
  }
  #pragma unroll
  for (int o = 16; o; o >>= 1) q += __shfl_xor(q, o, 32);
  #pragma unroll
  for (int o = 1; o < 32; o <<= 1) {
    hx ^= (unsigned int)__shfl_xor((int)hx, o, 32);
    hs += (unsigned int)__shfl_xor((int)hs, o, 32);
  }
  if (cg == 0) {
    qout[rg] = q;
    unsigned long long key = (((unsigned long long)hx << 32) | hs) & ~0xFFFULL;
    if (key == 0ULL) key = 0x123456789000ULL;
    const unsigned long long me = key | (unsigned long long)(rg + 1);
    unsigned int h = (hx ^ (hs * 0x9E3779B9u)) & (TSLOTS - 1);
    for (;;) {
      unsigned long long old = atomicCAS(&tab[h], 0ULL, me);
      if (old == 0ULL) break;
      if ((old & ~0xFFFULL) == key) {
        int r2 = (int)(old & 0xFFFULL) - 1;
        rowflag[rg] = 1; rowflag[r2] = 1;
        int e = atomicAdd(dupcnt, 1);
        if (e < DCAP) duplist[e] = make_int2(min(rg, r2), max(rg, r2));
      }
      h = (h + 1u) & (TSLOTS - 1);
    }
  }
}

// ---------------------------------------------------------------------------
// K2: split-bf16 MFMA all-pairs (virtual K=1536) + NT-Xent epilogue.
// NO LDS, NO barriers. Block = 8 waves (4x2) covering 128x64; wave = 32x32
// (2x2 frags). Grid 16x32 = 512 blocks -> 2 blocks/CU, 4 waves/SIMD.
// Depth-1 register ping-pong (8 fragments per buffer = 32 VGPR), named bufs.
// __launch_bounds__(512,4) caps VGPR at 128 -> no spills.
// ---------------------------------------------------------------------------
__global__ __launch_bounds__(512, 4) void k2_mfma(
    const unsigned short* __restrict__ Fhi, const unsigned short* __restrict__ Flo,
    const float* __restrict__ qv, const int* __restrict__ labels,
    const int* __restrict__ msk, const int* __restrict__ rowflag,
    const int* __restrict__ dupcnt, const int2* __restrict__ duplist,
    float4* __restrict__ partials)
{
  const int t = threadIdx.x;
  const int wid = t >> 6, lane = t & 63;
  const int gq = lane >> 4, c0 = lane & 15;
  const int bi = blockIdx.x, bj = blockIdx.y;
  const int wr = wid >> 1, wc = wid & 1;        // 4 x 2 waves
  const int wi0 = bi * 128 + wr * 32;           // wave's 32 i-rows
  const int wj0 = bj * 64 + wc * 32;            // wave's 32 j-cols

  size_t aoff[2], boff[2];
  #pragma unroll
  for (int f = 0; f < 2; ++f) {
    aoff[f] = (size_t)(wi0 + f * 16 + c0) * FEAT + gq * 8;
    boff[f] = (size_t)(wj0 + f * 16 + c0) * FEAT + gq * 8;
  }

  bf16x8 Ah0[2], Al0[2], Bh0[2], Bl0[2];
  bf16x8 Ah1[2], Al1[2], Bh1[2], Bl1[2];
  f32x4 acc[2][2];
  #pragma unroll
  for (int a = 0; a < 2; ++a)
    #pragma unroll
    for (int b = 0; b < 2; ++b) {
      acc[a][b][0] = 0.f; acc[a][b][1] = 0.f; acc[a][b][2] = 0.f; acc[a][b][3] = 0.f;
    }

#define LOADF(hb_, AH, AL, BH, BL)                                              \
  {                                                                             \
    const int kA_ = (hb_) * 32, kB_ = kA_ ^ 128;                                \
    _Pragma("unroll")                                                           \
    for (int f = 0; f < 2; ++f) {                                               \
      AH[f] = *reinterpret_cast<const bf16x8*>(Fhi + aoff[f] + kA_);            \
      AL[f] = *reinterpret_cast<const bf16x8*>(Flo + aoff[f] + kA_);            \
      BH[f] = *reinterpret_cast<const bf16x8*>(Fhi + boff[f] + kB_);            \
      BL[f] = *reinterpret_cast<const bf16x8*>(Flo + boff[f] + kB_);            \
    }                                                                           \
  }

#define MFMAS(AH, AL, BH, BL)                                                   \
  _Pragma("unroll")                                                             \
  for (int fa = 0; fa < 2; ++fa)                                                \
    _Pragma("unroll")                                                           \
    for (int fb = 0; fb < 2; ++fb) {                                            \
      acc[fa][fb] = __builtin_amdgcn_mfma_f32_16x16x32_bf16(                    \
          AH[fa], BH[fb], acc[fa][fb], 0, 0, 0);                                \
      acc[fa][fb] = __builtin_amdgcn_mfma_f32_16x16x32_bf16(                    \
          AH[fa], BL[fb], acc[fa][fb], 0, 0, 0);                                \
      acc[fa][fb] = __builtin_amdgcn_mfma_f32_16x16x32_bf16(                    \
          AL[fa], BH[fb], acc[fa][fb], 0, 0, 0);                                \
    }

  LOADF(0, Ah0, Al0, Bh0, Bl0);
  #pragma unroll 1
  for (int h2 = 0; h2 < 8; ++h2) {
    LOADF(h2 * 2 + 1, Ah1, Al1, Bh1, Bl1);
    MFMAS(Ah0, Al0, Bh0, Bl0);
    if (h2 < 7) LOADF(h2 * 2 + 2, Ah0, Al0, Bh0, Bl0);
    MFMAS(Ah1, Al1, Bh1, Bl1);
  }
#undef LOADF
#undef MFMAS

  // ---- epilogue: NT-Xent online merge per output row ----
  const int ndup = min(dupcnt[0], DCAP);
  int ljv[2]; float qjv[2]; int fjv[2]; int gjv[2];
  #pragma unroll
  for (int fb = 0; fb < 2; ++fb) {
    const int gj = wj0 + fb * 16 + c0;
    const int lab = labels[gj];
    ljv[fb] = (msk[gj] == 1 && lab >= 0) ? lab : -1;
    qjv[fb] = qv[gj];
    fjv[fb] = rowflag[gj];
    gjv[fb] = gj;
  }
  #pragma unroll
  for (int fa = 0; fa < 2; ++fa) {
    const int ibase = wi0 + fa * 16 + gq * 4;
    int li4[4], mi4[4], fi4[4]; float qi4[4];
    *reinterpret_cast<int4*>(li4)   = *reinterpret_cast<const int4*>(labels + ibase);
    *reinterpret_cast<int4*>(mi4)   = *reinterpret_cast<const int4*>(msk + ibase);
    *reinterpret_cast<int4*>(fi4)   = *reinterpret_cast<const int4*>(rowflag + ibase);
    *reinterpret_cast<float4*>(qi4) = *reinterpret_cast<const float4*>(qv + ibase);
    #pragma unroll
    for (int r = 0; r < 4; ++r) {
      const int gi = ibase + r;
      const int li = (mi4[r] == 1 && li4[r] >= 0) ? li4[r] : -1;
      float m = -INFINITY, n = 0.f, d = 0.f, c = 0.f;
      if (li >= 0) {
        #pragma unroll
        for (int fb = 0; fb < 2; ++fb) {
          const int lj = ljv[fb];
          bool inc = (lj >= 0) && (gi != gjv[fb]);
          if (inc && fi4[r] && fjv[fb]) {
            int plo = min(gi, gjv[fb]), phi = max(gi, gjv[fb]);
            for (int e = 0; e < ndup; ++e) {
              int2 p = duplist[e];
              if (p.x == plo && p.y == phi) { inc = false; break; }
            }
          }
          if (inc) {
            float S = acc[fa][fb][r];
            float l = 64.0f - 0.25f * (qi4[r] + qjv[fb] + S);
            float w = (li == lj) ? 1.0f : 0.0f;
            mergeState(m, n, d, l, w, 1.0f);
            c += w;
          }
        }
      }
      #pragma unroll
      for (int o = 1; o < 16; o <<= 1) {
        float m2 = __shfl_xor(m, o);
        float n2 = __shfl_xor(n, o);
        float d2 = __shfl_xor(d, o);
        float c2 = __shfl_xor(c, o);
        mergeState(m, n, d, m2, n2, d2);
        c += c2;
      }
      if (c0 == 0)
        partials[(size_t)(bj * 2 + wc) * NROWS + gi] = make_float4(m, n, d, c);
    }
  }
}

// ---------------------------------------------------------------------------
// K3a: merge 64 j-slices per row, per-block partial sums (no atomics).
// ---------------------------------------------------------------------------
__global__ __launch_bounds__(256) void k3a(const float4* __restrict__ partials,
                                           float2* __restrict__ bsums)
{
  const int r = blockIdx.x * 256 + threadIdx.x;
  float m = -INFINITY, n = 0.f, d = 0.f, c = 0.f;
  #pragma unroll 8
  for (int js = 0; js < NJS; ++js) {
    float4 p = partials[(size_t)js * NROWS + r];
    mergeState(m, n, d, p.x, p.y, p.z);
    c += p.w;
  }
  float lf = 0.f, ns = 0.f;
  if (c > 0.f) {
    lf = log2f(d) - log2f(n) + log2f(c);
    ns = 1.f;
  }
  #pragma unroll
  for (int o = 32; o; o >>= 1) {
    lf += __shfl_down(lf, o);
    ns += __shfl_down(ns, o);
  }
  __shared__ float sl[4], sn[4];
  const int wid = threadIdx.x >> 6;
  if ((threadIdx.x & 63) == 0) { sl[wid] = lf; sn[wid] = ns; }
  __syncthreads();
  if (threadIdx.x == 0)
    bsums[blockIdx.x] = make_float2(sl[0] + sl[1] + sl[2] + sl[3],
                                    sn[0] + sn[1] + sn[2] + sn[3]);
}

__global__ __launch_bounds__(64) void k3b(const float2* __restrict__ bsums,
                                          float* __restrict__ out)
{
  if (threadIdx.x == 0) {
    float L = 0.f, C = 0.f;
    for (int b = 0; b < 8; ++b) { L += bsums[b].x; C += bsums[b].y; }
    out[0] = L / fmaxf(C, 1.0f);
  }
}

// ---------------------------------------------------------------------------
extern "C" void kernel_launch(void* const* d_in, const int* in_sizes, int n_in,
                              void* d_out, int out_size, void* d_ws, size_t ws_size,
                              hipStream_t stream) {
  const float* E   = (const float*)d_in[0];
  const int*   tid = (const int*)d_in[1];
  const int*   msk = (const int*)d_in[2];
  const float* Wmu = (const float*)d_in[3];
  const float* bmu = (const float*)d_in[4];
  const float* Wsg = (const float*)d_in[5];
  const float* bsg = (const float*)d_in[6];

  unsigned char* w = (unsigned char*)d_ws;
  unsigned short* Ehi  = (unsigned short*)w;  w += (size_t)NROWS * HDIM * 2;   // 3 MB
  unsigned short* Elo  = (unsigned short*)w;  w += (size_t)NROWS * HDIM * 2;   // 3 MB
  unsigned short* Wthi = (unsigned short*)w;  w += (size_t)256 * HDIM * 2;     // 384 KB
  unsigned short* Wtlo = (unsigned short*)w;  w += (size_t)256 * HDIM * 2;     // 384 KB
  unsigned short* Fhi  = (unsigned short*)w;  w += (size_t)NROWS * FEAT * 2;   // 2 MB
  unsigned short* Flo  = (unsigned short*)w;  w += (size_t)NROWS * FEAT * 2;   // 2 MB
  float* Cpart         = (float*)w;           w += (size_t)4 * NROWS * 256 * 4; // 8 MB
  float* qv            = (float*)w;           w += (size_t)NROWS * 4;
  unsigned long long* tab = (unsigned long long*)w; w += (size_t)TSLOTS * 8;   // 64 KB
  int* rowflag         = (int*)w;             w += (size_t)NROWS * 4;
  int* dupcnt          = (int*)w;             w += 256;
  float2* bsums        = (float2*)w;          w += 256;
  int2* duplist        = (int2*)w;            w += (size_t)DCAP * 8;
  float4* partials     = (float4*)w;          w += (size_t)NJS * NROWS * 16;   // 2 MB

  k0_prep<<<873, 256, 0, stream>>>(E, Wmu, Wsg, Ehi, Elo, Wthi, Wtlo,
                                   tab, rowflag, dupcnt);
  k1m<<<256, 256, 0, stream>>>(Ehi, Elo, Wthi, Wtlo, Cpart);
  k1e<<<512, 256, 0, stream>>>(Cpart, bmu, bsg, Fhi, Flo, qv,
                               tab, rowflag, dupcnt, duplist);
  k2_mfma<<<dim3(16, 32), 512, 0, stream>>>(Fhi, Flo, qv, tid, msk, rowflag,
                                            dupcnt, duplist, partials);
  k3a<<<8, 256, 0, stream>>>(partials, bsums);
  k3b<<<1, 64, 0, stream>>>(bsums, (float*)d_out);
}

// Round 7
// 66.781 us; speedup vs baseline: 1.4742x; 1.4742x over previous
//
#include <hip/hip_runtime.h>
#include <math.h>

#define NROWS 2048
#define HDIM 768
#define DDIM 128
#define FEAT 512
#define DCAP 2048
#define TSLOTS 8192
#define NJS 64

typedef __attribute__((ext_vector_type(8))) short bf16x8;
typedef __attribute__((ext_vector_type(4))) float f32x4;

// Online logsumexp-style merge: state (m, n, d) <- merge with (m2, n2, d2).
__device__ __forceinline__ void mergeState(float& m, float& n, float& d,
                                           float m2, float n2, float d2) {
  float M = fmaxf(m, m2);
  float s1 = (m >= M) ? 1.0f : __expf(m - M);
  float s2 = (m2 >= M) ? 1.0f : __expf(m2 - M);
  n = n * s1 + n2 * s2;
  d = d * s1 + d2 * s2;
  m = M;
}

__device__ __forceinline__ unsigned short bfhi(float x) {
  unsigned int u = __float_as_uint(x);
  return (unsigned short)((u + 0x7fffu + ((u >> 16) & 1u)) >> 16);
}
__device__ __forceinline__ float bf2f(unsigned short h) {
  return __uint_as_float(((unsigned int)h) << 16);
}

__device__ __forceinline__ void gload16(const void* g, void* l) {
  __builtin_amdgcn_global_load_lds(
      (const __attribute__((address_space(1))) void*)g,
      (__attribute__((address_space(3))) void*)l, 16, 0, 0);
}

// ---------------------------------------------------------------------------
// k0_prep: (a) Ehi/Elo = bf16-split of relu(E); (b) Wthi/Wtlo = bf16-split of
// [Wmu|Wsg] transposed to [256 cols][768 k]; (c) clear hash table/flags.
// ---------------------------------------------------------------------------
__global__ __launch_bounds__(256) void k0_prep(
    const float* __restrict__ E, const float* __restrict__ Wmu,
    const float* __restrict__ Wsg,
    unsigned short* __restrict__ Ehi, unsigned short* __restrict__ Elo,
    unsigned short* __restrict__ Wthi, unsigned short* __restrict__ Wtlo,
    unsigned long long* __restrict__ tab, int* __restrict__ rowflag,
    int* __restrict__ dupcnt)
{
  const int bid = blockIdx.x, t = threadIdx.x;
  if (bid < 768) {
    const int base = bid * 2048 + t * 8;
    float4 v0 = *reinterpret_cast<const float4*>(E + base);
    float4 v1 = *reinterpret_cast<const float4*>(E + base + 4);
    const float v[8] = {v0.x, v0.y, v0.z, v0.w, v1.x, v1.y, v1.z, v1.w};
    unsigned short h[8], l[8];
    #pragma unroll
    for (int i = 0; i < 8; ++i) {
      float f = fmaxf(v[i], 0.f);
      h[i] = bfhi(f);
      l[i] = bfhi(f - bf2f(h[i]));
    }
    *reinterpret_cast<ushort4*>(Ehi + base)     = make_ushort4(h[0], h[1], h[2], h[3]);
    *reinterpret_cast<ushort4*>(Ehi + base + 4) = make_ushort4(h[4], h[5], h[6], h[7]);
    *reinterpret_cast<ushort4*>(Elo + base)     = make_ushort4(l[0], l[1], l[2], l[3]);
    *reinterpret_cast<ushort4*>(Elo + base + 4) = make_ushort4(l[4], l[5], l[6], l[7]);
  } else if (bid < 864) {
    const int tid = (bid - 768) * 256 + t;          // 0..24575
    const int c = tid / 96, kc = (tid % 96) * 8;
    unsigned short h[8], l[8];
    #pragma unroll
    for (int j = 0; j < 8; ++j) {
      float w = (c < 128) ? Wmu[(size_t)(kc + j) * DDIM + c]
                          : Wsg[(size_t)(kc + j) * DDIM + (c - 128)];
      h[j] = bfhi(w);
      l[j] = bfhi(w - bf2f(h[j]));
    }
    const size_t o = (size_t)c * HDIM + kc;
    *reinterpret_cast<ushort4*>(Wthi + o)     = make_ushort4(h[0], h[1], h[2], h[3]);
    *reinterpret_cast<ushort4*>(Wthi + o + 4) = make_ushort4(h[4], h[5], h[6], h[7]);
    *reinterpret_cast<ushort4*>(Wtlo + o)     = make_ushort4(l[0], l[1], l[2], l[3]);
    *reinterpret_cast<ushort4*>(Wtlo + o + 4) = make_ushort4(l[4], l[5], l[6], l[7]);
  } else if (bid < 872) {
    const int i4 = (bid - 864) * 1024 + t * 4;
    #pragma unroll
    for (int k = 0; k < 4; ++k) tab[i4 + k] = 0ULL;
    rowflag[(bid - 864) * 256 + t] = 0;
  } else {
    if (t == 0) dupcnt[0] = 0;
  }
}

// ---------------------------------------------------------------------------
// k1m: split-K MFMA projection GEMM. C[2048][256] partials over 4 K-splits.
// ---------------------------------------------------------------------------
__global__ __launch_bounds__(256) void k1m(
    const unsigned short* __restrict__ Ehi, const unsigned short* __restrict__ Elo,
    const unsigned short* __restrict__ Wthi, const unsigned short* __restrict__ Wtlo,
    float* __restrict__ Cpart)
{
  __shared__ unsigned short lds[24576];   // 48 KB = 2 buf x 12288
  const int t = threadIdx.x;
  const int bid = blockIdx.x;
  const int mt = bid & 31, nt = (bid >> 5) & 1, ks = bid >> 6;
  const int i0 = mt * 64, n0 = nt * 128, kbase = ks * 192;

  const unsigned short* gF[6];
  size_t goff[6];
  int lpb[6];
  #pragma unroll
  for (int rr = 0; rr < 6; ++rr) {
    if (rr < 2) {
      const int s = t, gq = s >> 6, row = s & 63;
      gF[rr] = rr ? Elo : Ehi;
      goff[rr] = (size_t)(i0 + row) * HDIM + kbase + gq * 8;
      lpb[rr] = rr * 2048 + (s & ~63) * 8;
    } else {
      const int s = (rr & 1) * 256 + t, gq = s >> 7, row = s & 127;
      gF[rr] = (rr >= 4) ? Wtlo : Wthi;
      goff[rr] = (size_t)(n0 + row) * HDIM + kbase + gq * 8;
      lpb[rr] = (rr >= 4 ? 8192 : 4096) + (s & ~63) * 8;
    }
  }

  f32x4 acc[2][4];
  #pragma unroll
  for (int a = 0; a < 2; ++a)
    #pragma unroll
    for (int b = 0; b < 4; ++b) {
      acc[a][b][0] = 0.f; acc[a][b][1] = 0.f; acc[a][b][2] = 0.f; acc[a][b][3] = 0.f;
    }

  const int wid = t >> 6, lane = t & 63;
  const int wr = wid >> 1, wc = wid & 1;
  const int gq = lane >> 4, c0 = lane & 15;

  auto stage = [&](int it, int buf) {
    unsigned short* lb = lds + buf * 12288;
    #pragma unroll
    for (int rr = 0; rr < 6; ++rr)
      gload16(gF[rr] + goff[rr] + it * 32, lb + lpb[rr]);
  };

  stage(0, 0);
  __syncthreads();

  for (int it = 0; it < 6; ++it) {
    if (it < 5) {
      stage(it + 1, (it + 1) & 1);
      asm volatile("s_waitcnt vmcnt(6)" ::: "memory");
    } else {
      asm volatile("s_waitcnt vmcnt(0)" ::: "memory");
    }
    __builtin_amdgcn_s_barrier();
    {
      const unsigned short* lb = lds + (it & 1) * 12288;
      bf16x8 ah[2], al[2], bh[4], bl[4];
      #pragma unroll
      for (int fa = 0; fa < 2; ++fa) {
        const int ia = gq * 512 + (wr * 32 + fa * 16 + c0) * 8;
        ah[fa] = *reinterpret_cast<const bf16x8*>(lb + ia);
        al[fa] = *reinterpret_cast<const bf16x8*>(lb + 2048 + ia);
      }
      #pragma unroll
      for (int fb = 0; fb < 4; ++fb) {
        const int ib = gq * 1024 + (wc * 64 + fb * 16 + c0) * 8;
        bh[fb] = *reinterpret_cast<const bf16x8*>(lb + 4096 + ib);
        bl[fb] = *reinterpret_cast<const bf16x8*>(lb + 8192 + ib);
      }
      #pragma unroll
      for (int fa = 0; fa < 2; ++fa)
        #pragma unroll
        for (int fb = 0; fb < 4; ++fb) {
          acc[fa][fb] = __builtin_amdgcn_mfma_f32_16x16x32_bf16(ah[fa], bh[fb], acc[fa][fb], 0, 0, 0);
          acc[fa][fb] = __builtin_amdgcn_mfma_f32_16x16x32_bf16(ah[fa], bl[fb], acc[fa][fb], 0, 0, 0);
          acc[fa][fb] = __builtin_amdgcn_mfma_f32_16x16x32_bf16(al[fa], bh[fb], acc[fa][fb], 0, 0, 0);
        }
    }
    __builtin_amdgcn_s_barrier();
  }

  #pragma unroll
  for (int fa = 0; fa < 2; ++fa)
    #pragma unroll
    for (int fb = 0; fb < 4; ++fb)
      #pragma unroll
      for (int r = 0; r < 4; ++r) {
        const int row = i0 + wr * 32 + fa * 16 + gq * 4 + r;
        const int col = n0 + wc * 64 + fb * 16 + c0;
        Cpart[((size_t)ks * NROWS + row) * 256 + col] = acc[fa][fb][r];
      }
}

// ---------------------------------------------------------------------------
// k1e: reduce 4 K-split partials -> mu/sigma -> features Fhi/Flo, q, and
// full-mu-vector duplicate hash (rowflag/duplist). Block = 4 rows.
// ---------------------------------------------------------------------------
__global__ __launch_bounds__(256) void k1e(
    const float* __restrict__ Cpart, const float* __restrict__ bmu,
    const float* __restrict__ bsg,
    unsigned short* __restrict__ Fhi, unsigned short* __restrict__ Flo,
    float* __restrict__ qout, unsigned long long* __restrict__ tab,
    int* __restrict__ rowflag, int* __restrict__ dupcnt,
    int2* __restrict__ duplist)
{
  __shared__ float sigL[4][DDIM];
  const int t = threadIdx.x;
  const int row = t >> 6, cg = t & 63, c4 = cg * 4;
  const int mat = c4 >> 7, colm = c4 & 127;
  const int rg = blockIdx.x * 4 + row;

  float v[4];
  {
    float4 s0 = *reinterpret_cast<const float4*>(&Cpart[((size_t)0 * NROWS + rg) * 256 + c4]);
    float4 s1 = *reinterpret_cast<const float4*>(&Cpart[((size_t)1 * NROWS + rg) * 256 + c4]);
    float4 s2 = *reinterpret_cast<const float4*>(&Cpart[((size_t)2 * NROWS + rg) * 256 + c4]);
    float4 s3 = *reinterpret_cast<const float4*>(&Cpart[((size_t)3 * NROWS + rg) * 256 + c4]);
    v[0] = ((s0.x + s1.x) + s2.x) + s3.x;
    v[1] = ((s0.y + s1.y) + s2.y) + s3.y;
    v[2] = ((s0.z + s1.z) + s2.z) + s3.z;
    v[3] = ((s0.w + s1.w) + s2.w) + s3.w;
  }

  if (mat == 1) {
    #pragma unroll
    for (int c = 0; c < 4; ++c) {
      float z = v[c] + bsg[colm + c];
      float s = (z > 0.f ? z + 1.0f : __expf(z)) + 1e-14f;
      sigL[row][colm + c] = s;
    }
  }
  __syncthreads();

  float q = 0.f;
  unsigned int hx = 0u, hs = 0u;
  if (mat == 0) {
    float f1[4], f2[4], f3[4], f4[4];
    #pragma unroll
    for (int c = 0; c < 4; ++c) {
      float mu = v[c] + bmu[colm + c];
      float s  = sigL[row][colm + c];
      float inv = 1.0f / s;
      f1[c] = inv;
      f2[c] = s + mu * mu;
      f3[c] = -2.0f * mu * inv;
      f4[c] = mu;
      q += mu * mu * inv;
      unsigned int b = __float_as_uint(mu);
      if (b == 0x80000000u) b = 0u;
      unsigned int hm = (b ^ ((unsigned int)(colm + c) * 0x9E3779B9u)) * 0x85EBCA6Bu;
      hm ^= hm >> 13;
      hx ^= hm;
      hs += hm * 0xC2B2AE35u;
    }
    const float* blocks[4] = {f1, f2, f3, f4};
    #pragma unroll
    for (int b = 0; b < 4; ++b) {
      const float* vv = blocks[b];
      unsigned short h[4], l[4];
      #pragma unroll
      for (int c = 0; c < 4; ++c) {
        h[c] = bfhi(vv[c]);
        l[c] = bfhi(vv[c] - bf2f(h[c]));
      }
      size_t off = (size_t)rg * FEAT + b * 128 + colm;
      *reinterpret_cast<ushort4*>(&Fhi[off]) = make_ushort4(h[0], h[1], h[2], h[3]);
      *reinterpret_cast<ushort4*>(&Flo[off]) = make_ushort4(l[0], l[1], l[2], l[3]);
    }
  }
  #pragma unroll
  for (int o = 16; o; o >>= 1) q += __shfl_xor(q, o, 32);
  #pragma unroll
  for (int o = 1; o < 32; o <<= 1) {
    hx ^= (unsigned int)__shfl_xor((int)hx, o, 32);
    hs += (unsigned int)__shfl_xor((int)hs, o, 32);
  }
  if (cg == 0) {
    qout[rg] = q;
    unsigned long long key = (((unsigned long long)hx << 32) | hs) & ~0xFFFULL;
    if (key == 0ULL) key = 0x123456789000ULL;
    const unsigned long long me = key | (unsigned long long)(rg + 1);
    unsigned int h = (hx ^ (hs * 0x9E3779B9u)) & (TSLOTS - 1);
    for (;;) {
      unsigned long long old = atomicCAS(&tab[h], 0ULL, me);
      if (old == 0ULL) break;
      if ((old & ~0xFFFULL) == key) {
        int r2 = (int)(old & 0xFFFULL) - 1;
        rowflag[rg] = 1; rowflag[r2] = 1;
        int e = atomicAdd(dupcnt, 1);
        if (e < DCAP) duplist[e] = make_int2(min(rg, r2), max(rg, r2));
      }
      h = (h + 1u) & (TSLOTS - 1);
    }
  }
}

// ---------------------------------------------------------------------------
// K2: split-bf16 MFMA all-pairs (virtual K=1536) + NT-Xent epilogue.
// Tile 128x128, grid 256 (1 block/CU), 512 threads = 8 waves (2M x 4N),
// wave tile 64x32. Phys-K chunk 32, TRIPLE-buffered LDS (3 x 32 KB),
// prefetch depth 2, counted vmcnt(8) (never 0 until tail). Per chunk:
// 4 gload_lds/thread -> barrier -> 12 ds_read_b128 (K-major, conflict-free)
// -> lgkmcnt(0)+sched_barrier -> setprio(1) 24 MFMA setprio(0) -> barrier.
// XCD-chunked block swizzle (bijective, 256%8==0).
// ---------------------------------------------------------------------------
__global__ __launch_bounds__(512, 2) void k2_mfma(
    const unsigned short* __restrict__ Fhi, const unsigned short* __restrict__ Flo,
    const float* __restrict__ qv, const int* __restrict__ labels,
    const int* __restrict__ msk, const int* __restrict__ rowflag,
    const int* __restrict__ dupcnt, const int2* __restrict__ duplist,
    float4* __restrict__ partials)
{
  __shared__ unsigned short lds[3 * 16384];   // 96 KB
  const int t = threadIdx.x;
  // XCD-chunked swizzle: 8 XCDs x 32 contiguous blocks
  const int orig = blockIdx.x;
  const int wg = (orig & 7) * 32 + (orig >> 3);
  const int bi = wg >> 4, bj = wg & 15;
  const int i0 = bi * 128, j0 = bj * 128;
  const int wid = t >> 6, lane = t & 63;
  const int wr = wid >> 2, wc = wid & 3;      // 2M x 4N waves, wave 64x32
  const int gq = lane >> 4, c0 = lane & 15;

  // staging: thread t owns LDS 16B-slot t of each region. slot -> row=t&127,
  // kq=t>>7 (K-major layout: ushort off = (kq*128+row)*8 == t*8).
  const int srow = t & 127, skq = t >> 7;
  const size_t gA = (size_t)(i0 + srow) * FEAT + skq * 8;
  const size_t gB = (size_t)(j0 + srow) * FEAT + skq * 8;
  const int lslot = (t & ~63) * 8;            // wave-uniform ushort base

  f32x4 acc[4][2];
  #pragma unroll
  for (int a = 0; a < 4; ++a)
    #pragma unroll
    for (int b = 0; b < 2; ++b) {
      acc[a][b][0] = 0.f; acc[a][b][1] = 0.f; acc[a][b][2] = 0.f; acc[a][b][3] = 0.f;
    }

  auto stage = [&](int c) {
    const int kb = c * 32;
    unsigned short* lb = lds + (c % 3) * 16384;
    gload16(Fhi + gA + kb,          lb + lslot);            // Ahi
    gload16(Flo + gA + kb,          lb + 4096 + lslot);     // Alo
    gload16(Fhi + gB + (kb ^ 128),  lb + 8192 + lslot);     // Bhi (feat swap)
    gload16(Flo + gB + (kb ^ 128),  lb + 12288 + lslot);    // Blo
  };

  stage(0);
  stage(1);

  #pragma unroll
  for (int c = 0; c < 16; ++c) {
    if (c < 14) {
      stage(c + 2);
      asm volatile("s_waitcnt vmcnt(8)" ::: "memory");
    } else if (c == 14) {
      asm volatile("s_waitcnt vmcnt(4)" ::: "memory");
    } else {
      asm volatile("s_waitcnt vmcnt(0)" ::: "memory");
    }
    __builtin_amdgcn_s_barrier();               // chunk c fully in LDS
    {
      const unsigned short* lb = lds + (c % 3) * 16384;
      bf16x8 ah[4], al[4], bh[2], bl[2];
      #pragma unroll
      for (int fa = 0; fa < 4; ++fa) {
        const int off = (gq * 128 + wr * 64 + fa * 16 + c0) * 8;
        ah[fa] = *reinterpret_cast<const bf16x8*>(lb + off);
        al[fa] = *reinterpret_cast<const bf16x8*>(lb + 4096 + off);
      }
      #pragma unroll
      for (int fb = 0; fb < 2; ++fb) {
        const int off = (gq * 128 + wc * 32 + fb * 16 + c0) * 8;
        bh[fb] = *reinterpret_cast<const bf16x8*>(lb + 8192 + off);
        bl[fb] = *reinterpret_cast<const bf16x8*>(lb + 12288 + off);
      }
      asm volatile("s_waitcnt lgkmcnt(0)" ::: "memory");
      __builtin_amdgcn_sched_barrier(0);
      __builtin_amdgcn_s_setprio(1);
      #pragma unroll
      for (int fa = 0; fa < 4; ++fa)
        #pragma unroll
        for (int fb = 0; fb < 2; ++fb) {
          acc[fa][fb] = __builtin_amdgcn_mfma_f32_16x16x32_bf16(ah[fa], bh[fb], acc[fa][fb], 0, 0, 0);
          acc[fa][fb] = __builtin_amdgcn_mfma_f32_16x16x32_bf16(ah[fa], bl[fb], acc[fa][fb], 0, 0, 0);
          acc[fa][fb] = __builtin_amdgcn_mfma_f32_16x16x32_bf16(al[fa], bh[fb], acc[fa][fb], 0, 0, 0);
        }
      __builtin_amdgcn_s_setprio(0);
    }
    __builtin_amdgcn_s_barrier();               // frags consumed; buffer reusable
  }

  // ---- epilogue: NT-Xent online merge per output row ----
  const int ndup = min(dupcnt[0], DCAP);
  int ljv[2]; float qjv[2]; int fjv[2]; int gjv[2];
  #pragma unroll
  for (int fb = 0; fb < 2; ++fb) {
    const int gj = j0 + wc * 32 + fb * 16 + c0;
    const int lab = labels[gj];
    ljv[fb] = (msk[gj] == 1 && lab >= 0) ? lab : -1;
    qjv[fb] = qv[gj];
    fjv[fb] = rowflag[gj];
    gjv[fb] = gj;
  }
  #pragma unroll
  for (int fa = 0; fa < 4; ++fa) {
    const int ibase = i0 + wr * 64 + fa * 16 + gq * 4;
    int li4[4], mi4[4], fi4[4]; float qi4[4];
    *reinterpret_cast<int4*>(li4)   = *reinterpret_cast<const int4*>(labels + ibase);
    *reinterpret_cast<int4*>(mi4)   = *reinterpret_cast<const int4*>(msk + ibase);
    *reinterpret_cast<int4*>(fi4)   = *reinterpret_cast<const int4*>(rowflag + ibase);
    *reinterpret_cast<float4*>(qi4) = *reinterpret_cast<const float4*>(qv + ibase);
    #pragma unroll
    for (int r = 0; r < 4; ++r) {
      const int gi = ibase + r;
      const int li = (mi4[r] == 1 && li4[r] >= 0) ? li4[r] : -1;
      float m = -INFINITY, n = 0.f, d = 0.f, c = 0.f;
      if (li >= 0) {
        #pragma unroll
        for (int fb = 0; fb < 2; ++fb) {
          const int lj = ljv[fb];
          bool inc = (lj >= 0) && (gi != gjv[fb]);
          if (inc && fi4[r] && fjv[fb]) {
            int plo = min(gi, gjv[fb]), phi = max(gi, gjv[fb]);
            for (int e = 0; e < ndup; ++e) {
              int2 p = duplist[e];
              if (p.x == plo && p.y == phi) { inc = false; break; }
            }
          }
          if (inc) {
            float S = acc[fa][fb][r];
            float l = 64.0f - 0.25f * (qi4[r] + qjv[fb] + S);
            float w = (li == lj) ? 1.0f : 0.0f;
            mergeState(m, n, d, l, w, 1.0f);
            c += w;
          }
        }
      }
      #pragma unroll
      for (int o = 1; o < 16; o <<= 1) {
        float m2 = __shfl_xor(m, o);
        float n2 = __shfl_xor(n, o);
        float d2 = __shfl_xor(d, o);
        float c2 = __shfl_xor(c, o);
        mergeState(m, n, d, m2, n2, d2);
        c += c2;
      }
      if (c0 == 0)
        partials[(size_t)(bj * 4 + wc) * NROWS + gi] = make_float4(m, n, d, c);
    }
  }
}

// ---------------------------------------------------------------------------
// K3a: merge 64 j-slices per row, per-block partial sums (no atomics).
// ---------------------------------------------------------------------------
__global__ __launch_bounds__(256) void k3a(const float4* __restrict__ partials,
                                           float2* __restrict__ bsums)
{
  const int r = blockIdx.x * 256 + threadIdx.x;
  float m = -INFINITY, n = 0.f, d = 0.f, c = 0.f;
  #pragma unroll 8
  for (int js = 0; js < NJS; ++js) {
    float4 p = partials[(size_t)js * NROWS + r];
    mergeState(m, n, d, p.x, p.y, p.z);
    c += p.w;
  }
  float lf = 0.f, ns = 0.f;
  if (c > 0.f) {
    lf = log2f(d) - log2f(n) + log2f(c);
    ns = 1.f;
  }
  #pragma unroll
  for (int o = 32; o; o >>= 1) {
    lf += __shfl_down(lf, o);
    ns += __shfl_down(ns, o);
  }
  __shared__ float sl[4], sn[4];
  const int wid = threadIdx.x >> 6;
  if ((threadIdx.x & 63) == 0) { sl[wid] = lf; sn[wid] = ns; }
  __syncthreads();
  if (threadIdx.x == 0)
    bsums[blockIdx.x] = make_float2(sl[0] + sl[1] + sl[2] + sl[3],
                                    sn[0] + sn[1] + sn[2] + sn[3]);
}

__global__ __launch_bounds__(64) void k3b(const float2* __restrict__ bsums,
                                          float* __restrict__ out)
{
  if (threadIdx.x == 0) {
    float L = 0.f, C = 0.f;
    for (int b = 0; b < 8; ++b) { L += bsums[b].x; C += bsums[b].y; }
    out[0] = L / fmaxf(C, 1.0f);
  }
}

// ---------------------------------------------------------------------------
extern "C" void kernel_launch(void* const* d_in, const int* in_sizes, int n_in,
                              void* d_out, int out_size, void* d_ws, size_t ws_size,
                              hipStream_t stream) {
  const float* E   = (const float*)d_in[0];
  const int*   tid = (const int*)d_in[1];
  const int*   msk = (const int*)d_in[2];
  const float* Wmu = (const float*)d_in[3];
  const float* bmu = (const float*)d_in[4];
  const float* Wsg = (const float*)d_in[5];
  const float* bsg = (const float*)d_in[6];

  unsigned char* w = (unsigned char*)d_ws;
  unsigned short* Ehi  = (unsigned short*)w;  w += (size_t)NROWS * HDIM * 2;   // 3 MB
  unsigned short* Elo  = (unsigned short*)w;  w += (size_t)NROWS * HDIM * 2;   // 3 MB
  unsigned short* Wthi = (unsigned short*)w;  w += (size_t)256 * HDIM * 2;     // 384 KB
  unsigned short* Wtlo = (unsigned short*)w;  w += (size_t)256 * HDIM * 2;     // 384 KB
  unsigned short* Fhi  = (unsigned short*)w;  w += (size_t)NROWS * FEAT * 2;   // 2 MB
  unsigned short* Flo  = (unsigned short*)w;  w += (size_t)NROWS * FEAT * 2;   // 2 MB
  float* Cpart         = (float*)w;           w += (size_t)4 * NROWS * 256 * 4; // 8 MB
  float* qv            = (float*)w;           w += (size_t)NROWS * 4;
  unsigned long long* tab = (unsigned long long*)w; w += (size_t)TSLOTS * 8;   // 64 KB
  int* rowflag         = (int*)w;             w += (size_t)NROWS * 4;
  int* dupcnt          = (int*)w;             w += 256;
  float2* bsums        = (float2*)w;          w += 256;
  int2* duplist        = (int2*)w;            w += (size_t)DCAP * 8;
  float4* partials     = (float4*)w;          w += (size_t)NJS * NROWS * 16;   // 2 MB

  k0_prep<<<873, 256, 0, stream>>>(E, Wmu, Wsg, Ehi, Elo, Wthi, Wtlo,
                                   tab, rowflag, dupcnt);
  k1m<<<256, 256, 0, stream>>>(Ehi, Elo, Wthi, Wtlo, Cpart);
  k1e<<<512, 256, 0, stream>>>(Cpart, bmu, bsg, Fhi, Flo, qv,
                               tab, rowflag, dupcnt, duplist);
  k2_mfma<<<256, 512, 0, stream>>>(Fhi, Flo, qv, tid, msk, rowflag,
                                   dupcnt, duplist, partials);
  k3a<<<8, 256, 0, stream>>>(partials, bsums);
  k3b<<<1, 64, 0, stream>>>(bsums, (float*)d_out);
}

// Round 8
// 59.602 us; speedup vs baseline: 1.6518x; 1.1204x over previous
//
#include <hip/hip_runtime.h>
#include <math.h>

#define NROWS 2048
#define HDIM 768
#define DDIM 128
#define FEAT 512
#define DCAP 2048
#define TSLOTS 8192
#define NJS 64

typedef __attribute__((ext_vector_type(8))) short bf16x8;
typedef __attribute__((ext_vector_type(4))) float f32x4;

// Online logsumexp-style merge: state (m, n, d) <- merge with (m2, n2, d2).
__device__ __forceinline__ void mergeState(float& m, float& n, float& d,
                                           float m2, float n2, float d2) {
  float M = fmaxf(m, m2);
  float s1 = (m >= M) ? 1.0f : __expf(m - M);
  float s2 = (m2 >= M) ? 1.0f : __expf(m2 - M);
  n = n * s1 + n2 * s2;
  d = d * s1 + d2 * s2;
  m = M;
}

__device__ __forceinline__ unsigned short bfhi(float x) {
  unsigned int u = __float_as_uint(x);
  return (unsigned short)((u + 0x7fffu + ((u >> 16) & 1u)) >> 16);
}
__device__ __forceinline__ float bf2f(unsigned short h) {
  return __uint_as_float(((unsigned int)h) << 16);
}

__device__ __forceinline__ void gload16(const void* g, void* l) {
  __builtin_amdgcn_global_load_lds(
      (const __attribute__((address_space(1))) void*)g,
      (__attribute__((address_space(3))) void*)l, 16, 0, 0);
}

// ---------------------------------------------------------------------------
// k0_prep: (a) Ehi/Elo = bf16-split of relu(E); (b) Wthi/Wtlo = bf16-split of
// [Wmu|Wsg] transposed to [256 cols][768 k]; (c) clear hash table/flags.
// ---------------------------------------------------------------------------
__global__ __launch_bounds__(256) void k0_prep(
    const float* __restrict__ E, const float* __restrict__ Wmu,
    const float* __restrict__ Wsg,
    unsigned short* __restrict__ Ehi, unsigned short* __restrict__ Elo,
    unsigned short* __restrict__ Wthi, unsigned short* __restrict__ Wtlo,
    unsigned long long* __restrict__ tab, int* __restrict__ rowflag,
    int* __restrict__ dupcnt)
{
  const int bid = blockIdx.x, t = threadIdx.x;
  if (bid < 768) {
    const int base = bid * 2048 + t * 8;
    float4 v0 = *reinterpret_cast<const float4*>(E + base);
    float4 v1 = *reinterpret_cast<const float4*>(E + base + 4);
    const float v[8] = {v0.x, v0.y, v0.z, v0.w, v1.x, v1.y, v1.z, v1.w};
    unsigned short h[8], l[8];
    #pragma unroll
    for (int i = 0; i < 8; ++i) {
      float f = fmaxf(v[i], 0.f);
      h[i] = bfhi(f);
      l[i] = bfhi(f - bf2f(h[i]));
    }
    *reinterpret_cast<ushort4*>(Ehi + base)     = make_ushort4(h[0], h[1], h[2], h[3]);
    *reinterpret_cast<ushort4*>(Ehi + base + 4) = make_ushort4(h[4], h[5], h[6], h[7]);
    *reinterpret_cast<ushort4*>(Elo + base)     = make_ushort4(l[0], l[1], l[2], l[3]);
    *reinterpret_cast<ushort4*>(Elo + base + 4) = make_ushort4(l[4], l[5], l[6], l[7]);
  } else if (bid < 864) {
    const int tid = (bid - 768) * 256 + t;          // 0..24575
    const int c = tid / 96, kc = (tid % 96) * 8;
    unsigned short h[8], l[8];
    #pragma unroll
    for (int j = 0; j < 8; ++j) {
      float w = (c < 128) ? Wmu[(size_t)(kc + j) * DDIM + c]
                          : Wsg[(size_t)(kc + j) * DDIM + (c - 128)];
      h[j] = bfhi(w);
      l[j] = bfhi(w - bf2f(h[j]));
    }
    const size_t o = (size_t)c * HDIM + kc;
    *reinterpret_cast<ushort4*>(Wthi + o)     = make_ushort4(h[0], h[1], h[2], h[3]);
    *reinterpret_cast<ushort4*>(Wthi + o + 4) = make_ushort4(h[4], h[5], h[6], h[7]);
    *reinterpret_cast<ushort4*>(Wtlo + o)     = make_ushort4(l[0], l[1], l[2], l[3]);
    *reinterpret_cast<ushort4*>(Wtlo + o + 4) = make_ushort4(l[4], l[5], l[6], l[7]);
  } else if (bid < 872) {
    const int i4 = (bid - 864) * 1024 + t * 4;
    #pragma unroll
    for (int k = 0; k < 4; ++k) tab[i4 + k] = 0ULL;
    rowflag[(bid - 864) * 256 + t] = 0;
  } else {
    if (t == 0) dupcnt[0] = 0;
  }
}

// ---------------------------------------------------------------------------
// k1m: split-K MFMA projection GEMM. C[2048][256] partials over 4 K-splits.
// ---------------------------------------------------------------------------
__global__ __launch_bounds__(256) void k1m(
    const unsigned short* __restrict__ Ehi, const unsigned short* __restrict__ Elo,
    const unsigned short* __restrict__ Wthi, const unsigned short* __restrict__ Wtlo,
    float* __restrict__ Cpart)
{
  __shared__ unsigned short lds[24576];   // 48 KB = 2 buf x 12288
  const int t = threadIdx.x;
  const int bid = blockIdx.x;
  const int mt = bid & 31, nt = (bid >> 5) & 1, ks = bid >> 6;
  const int i0 = mt * 64, n0 = nt * 128, kbase = ks * 192;

  const unsigned short* gF[6];
  size_t goff[6];
  int lpb[6];
  #pragma unroll
  for (int rr = 0; rr < 6; ++rr) {
    if (rr < 2) {
      const int s = t, gq = s >> 6, row = s & 63;
      gF[rr] = rr ? Elo : Ehi;
      goff[rr] = (size_t)(i0 + row) * HDIM + kbase + gq * 8;
      lpb[rr] = rr * 2048 + (s & ~63) * 8;
    } else {
      const int s = (rr & 1) * 256 + t, gq = s >> 7, row = s & 127;
      gF[rr] = (rr >= 4) ? Wtlo : Wthi;
      goff[rr] = (size_t)(n0 + row) * HDIM + kbase + gq * 8;
      lpb[rr] = (rr >= 4 ? 8192 : 4096) + (s & ~63) * 8;
    }
  }

  f32x4 acc[2][4];
  #pragma unroll
  for (int a = 0; a < 2; ++a)
    #pragma unroll
    for (int b = 0; b < 4; ++b) {
      acc[a][b][0] = 0.f; acc[a][b][1] = 0.f; acc[a][b][2] = 0.f; acc[a][b][3] = 0.f;
    }

  const int wid = t >> 6, lane = t & 63;
  const int wr = wid >> 1, wc = wid & 1;
  const int gq = lane >> 4, c0 = lane & 15;

  auto stage = [&](int it, int buf) {
    unsigned short* lb = lds + buf * 12288;
    #pragma unroll
    for (int rr = 0; rr < 6; ++rr)
      gload16(gF[rr] + goff[rr] + it * 32, lb + lpb[rr]);
  };

  stage(0, 0);
  __syncthreads();

  for (int it = 0; it < 6; ++it) {
    if (it < 5) {
      stage(it + 1, (it + 1) & 1);
      asm volatile("s_waitcnt vmcnt(6)" ::: "memory");
    } else {
      asm volatile("s_waitcnt vmcnt(0)" ::: "memory");
    }
    __builtin_amdgcn_s_barrier();
    {
      const unsigned short* lb = lds + (it & 1) * 12288;
      bf16x8 ah[2], al[2], bh[4], bl[4];
      #pragma unroll
      for (int fa = 0; fa < 2; ++fa) {
        const int ia = gq * 512 + (wr * 32 + fa * 16 + c0) * 8;
        ah[fa] = *reinterpret_cast<const bf16x8*>(lb + ia);
        al[fa] = *reinterpret_cast<const bf16x8*>(lb + 2048 + ia);
      }
      #pragma unroll
      for (int fb = 0; fb < 4; ++fb) {
        const int ib = gq * 1024 + (wc * 64 + fb * 16 + c0) * 8;
        bh[fb] = *reinterpret_cast<const bf16x8*>(lb + 4096 + ib);
        bl[fb] = *reinterpret_cast<const bf16x8*>(lb + 8192 + ib);
      }
      #pragma unroll
      for (int fa = 0; fa < 2; ++fa)
        #pragma unroll
        for (int fb = 0; fb < 4; ++fb) {
          acc[fa][fb] = __builtin_amdgcn_mfma_f32_16x16x32_bf16(ah[fa], bh[fb], acc[fa][fb], 0, 0, 0);
          acc[fa][fb] = __builtin_amdgcn_mfma_f32_16x16x32_bf16(ah[fa], bl[fb], acc[fa][fb], 0, 0, 0);
          acc[fa][fb] = __builtin_amdgcn_mfma_f32_16x16x32_bf16(al[fa], bh[fb], acc[fa][fb], 0, 0, 0);
        }
    }
    __builtin_amdgcn_s_barrier();
  }

  #pragma unroll
  for (int fa = 0; fa < 2; ++fa)
    #pragma unroll
    for (int fb = 0; fb < 4; ++fb)
      #pragma unroll
      for (int r = 0; r < 4; ++r) {
        const int row = i0 + wr * 32 + fa * 16 + gq * 4 + r;
        const int col = n0 + wc * 64 + fb * 16 + c0;
        Cpart[((size_t)ks * NROWS + row) * 256 + col] = acc[fa][fb][r];
      }
}

// ---------------------------------------------------------------------------
// k1e: reduce 4 K-split partials -> mu/sigma -> features Fhi/Flo, q, and
// full-mu-vector duplicate hash (rowflag/duplist). Block = 4 rows.
// ---------------------------------------------------------------------------
__global__ __launch_bounds__(256) void k1e(
    const float* __restrict__ Cpart, const float* __restrict__ bmu,
    const float* __restrict__ bsg,
    unsigned short* __restrict__ Fhi, unsigned short* __restrict__ Flo,
    float* __restrict__ qout, unsigned long long* __restrict__ tab,
    int* __restrict__ rowflag, int* __restrict__ dupcnt,
    int2* __restrict__ duplist)
{
  __shared__ float sigL[4][DDIM];
  const int t = threadIdx.x;
  const int row = t >> 6, cg = t & 63, c4 = cg * 4;
  const int mat = c4 >> 7, colm = c4 & 127;
  const int rg = blockIdx.x * 4 + row;

  float v[4];
  {
    float4 s0 = *reinterpret_cast<const float4*>(&Cpart[((size_t)0 * NROWS + rg) * 256 + c4]);
    float4 s1 = *reinterpret_cast<const float4*>(&Cpart[((size_t)1 * NROWS + rg) * 256 + c4]);
    float4 s2 = *reinterpret_cast<const float4*>(&Cpart[((size_t)2 * NROWS + rg) * 256 + c4]);
    float4 s3 = *reinterpret_cast<const float4*>(&Cpart[((size_t)3 * NROWS + rg) * 256 + c4]);
    v[0] = ((s0.x + s1.x) + s2.x) + s3.x;
    v[1] = ((s0.y + s1.y) + s2.y) + s3.y;
    v[2] = ((s0.z + s1.z) + s2.z) + s3.z;
    v[3] = ((s0.w + s1.w) + s2.w) + s3.w;
  }

  if (mat == 1) {
    #pragma unroll
    for (int c = 0; c < 4; ++c) {
      float z = v[c] + bsg[colm + c];
      float s = (z > 0.f ? z + 1.0f : __expf(z)) + 1e-14f;
      sigL[row][colm + c] = s;
    }
  }
  __syncthreads();

  float q = 0.f;
  unsigned int hx = 0u, hs = 0u;
  if (mat == 0) {
    float f1[4], f2[4], f3[4], f4[4];
    #pragma unroll
    for (int c = 0; c < 4; ++c) {
      float mu = v[c] + bmu[colm + c];
      float s  = sigL[row][colm + c];
      float inv = 1.0f / s;
      f1[c] = inv;
      f2[c] = s + mu * mu;
      f3[c] = -2.0f * mu * inv;
      f4[c] = mu;
      q += mu * mu * inv;
      unsigned int b = __float_as_uint(mu);
      if (b == 0x80000000u) b = 0u;
      unsigned int hm = (b ^ ((unsigned int)(colm + c) * 0x9E3779B9u)) * 0x85EBCA6Bu;
      hm ^= hm >> 13;
      hx ^= hm;
      hs += hm * 0xC2B2AE35u;
    }
    const float* blocks[4] = {f1, f2, f3, f4};
    #pragma unroll
    for (int b = 0; b < 4; ++b) {
      const float* vv = blocks[b];
      unsigned short h[4], l[4];
      #pragma unroll
      for (int c = 0; c < 4; ++c) {
        h[c] = bfhi(vv[c]);
        l[c] = bfhi(vv[c] - bf2f(h[c]));
      }
      size_t off = (size_t)rg * FEAT + b * 128 + colm;
      *reinterpret_cast<ushort4*>(&Fhi[off]) = make_ushort4(h[0], h[1], h[2], h[3]);
      *reinterpret_cast<ushort4*>(&Flo[off]) = make_ushort4(l[0], l[1], l[2], l[3]);
    }
  }
  #pragma unroll
  for (int o = 16; o; o >>= 1) q += __shfl_xor(q, o, 32);
  #pragma unroll
  for (int o = 1; o < 32; o <<= 1) {
    hx ^= (unsigned int)__shfl_xor((int)hx, o, 32);
    hs += (unsigned int)__shfl_xor((int)hs, o, 32);
  }
  if (cg == 0) {
    qout[rg] = q;
    unsigned long long key = (((unsigned long long)hx << 32) | hs) & ~0xFFFULL;
    if (key == 0ULL) key = 0x123456789000ULL;
    const unsigned long long me = key | (unsigned long long)(rg + 1);
    unsigned int h = (hx ^ (hs * 0x9E3779B9u)) & (TSLOTS - 1);
    for (;;) {
      unsigned long long old = atomicCAS(&tab[h], 0ULL, me);
      if (old == 0ULL) break;
      if ((old & ~0xFFFULL) == key) {
        int r2 = (int)(old & 0xFFFULL) - 1;
        rowflag[rg] = 1; rowflag[r2] = 1;
        int e = atomicAdd(dupcnt, 1);
        if (e < DCAP) duplist[e] = make_int2(min(rg, r2), max(rg, r2));
      }
      h = (h + 1u) & (TSLOTS - 1);
    }
  }
}

// ---------------------------------------------------------------------------
// K2: split-bf16 MFMA all-pairs (virtual K=1536) + NT-Xent epilogue.
// Tile 128x128, grid 256 (1 block/CU), 512 threads = 8 waves (2M x 4N).
// K-chunk 64 ushorts (128 B/row). COALESCED staging: one gload16 = 8 rows x
// one full 128B line (lane l: row l>>3, 16B-block (l&7)^(l>>3) -- XOR swizzle
// stays within the row's line). LDS row-major [128][64] with slot s of row r
// holding global k-block s^(r&7); ds_read slot = (kc*4+gq)^(c0&7) -> 2
// lanes/bank (free). Dbuf 2x64KB, depth-1 prefetch, counted vmcnt(8),
// raw barriers (16 total), setprio around MFMA. B feature-swap = chunk c^2.
// ---------------------------------------------------------------------------
__global__ __launch_bounds__(512, 2) void k2_mfma(
    const unsigned short* __restrict__ Fhi, const unsigned short* __restrict__ Flo,
    const float* __restrict__ qv, const int* __restrict__ labels,
    const int* __restrict__ msk, const int* __restrict__ rowflag,
    const int* __restrict__ dupcnt, const int2* __restrict__ duplist,
    float4* __restrict__ partials)
{
  __shared__ unsigned short lds[2 * 32768];   // 128 KB
  const int t = threadIdx.x;
  // XCD-chunked swizzle: 8 XCDs x 32 contiguous blocks
  const int orig = blockIdx.x;
  const int wg = (orig & 7) * 32 + (orig >> 3);
  const int bi = wg >> 4, bj = wg & 15;
  const int i0 = bi * 128, j0 = bj * 128;
  const int wid = t >> 6, lane = t & 63;
  const int wr = wid >> 2, wc = wid & 3;      // 2M x 4N waves, wave tile 64x32
  const int gq = lane >> 4, c0 = lane & 15;

  // ---- staging geometry (coalesced, swizzled source within the line) ----
  const int l8 = lane >> 3, l7 = lane & 7;
  const int kperm = (l7 ^ l8) * 8;            // ushort offset within 128B row-chunk
  const size_t gA0 = (size_t)(i0 + wid * 8 + l8) * FEAT + kperm;        // instr wid
  const size_t gA1 = (size_t)(i0 + (wid + 8) * 8 + l8) * FEAT + kperm;  // instr wid+8
  const size_t gB0 = (size_t)(j0 + wid * 8 + l8) * FEAT + kperm;
  const size_t gB1 = (size_t)(j0 + (wid + 8) * 8 + l8) * FEAT + kperm;
  const int ld0 = wid * 512;                  // wave-uniform LDS instr base (ushorts)
  const int ld1 = (wid + 8) * 512;

  f32x4 acc[4][2];
  #pragma unroll
  for (int a = 0; a < 4; ++a)
    #pragma unroll
    for (int b = 0; b < 2; ++b) {
      acc[a][b][0] = 0.f; acc[a][b][1] = 0.f; acc[a][b][2] = 0.f; acc[a][b][3] = 0.f;
    }

  auto stage = [&](int c) {
    unsigned short* lb = lds + (c & 1) * 32768;
    const int ka = c * 64;                    // A global chunk offset (ushorts)
    const int kb = (c ^ 2) * 64;              // B feature-block swap
    gload16(Fhi + gA0 + ka, lb + ld0);                 // Ahi
    gload16(Flo + gA0 + ka, lb + 8192 + ld0);          // Alo
    gload16(Fhi + gB0 + kb, lb + 16384 + ld0);         // Bhi
    gload16(Flo + gB0 + kb, lb + 24576 + ld0);         // Blo
    gload16(Fhi + gA1 + ka, lb + ld1);
    gload16(Flo + gA1 + ka, lb + 8192 + ld1);
    gload16(Fhi + gB1 + kb, lb + 16384 + ld1);
    gload16(Flo + gB1 + kb, lb + 24576 + ld1);
  };

  stage(0);

  for (int c = 0; c < 8; ++c) {
    if (c < 7) {
      stage(c + 1);
      asm volatile("s_waitcnt vmcnt(8)" ::: "memory");
    } else {
      asm volatile("s_waitcnt vmcnt(0)" ::: "memory");
    }
    __builtin_amdgcn_s_barrier();             // chunk c fully in LDS
    const unsigned short* lb = lds + (c & 1) * 32768;
    #pragma unroll
    for (int kc = 0; kc < 2; ++kc) {
      bf16x8 ah[4], al[4], bh[2], bl[2];
      const int slot = ((kc * 4 + gq) ^ (c0 & 7)) * 8;
      #pragma unroll
      for (int fa = 0; fa < 4; ++fa) {
        const int off = (wr * 64 + fa * 16 + c0) * 64 + slot;
        ah[fa] = *reinterpret_cast<const bf16x8*>(lb + off);
        al[fa] = *reinterpret_cast<const bf16x8*>(lb + 8192 + off);
      }
      #pragma unroll
      for (int fb = 0; fb < 2; ++fb) {
        const int off = (wc * 32 + fb * 16 + c0) * 64 + slot;
        bh[fb] = *reinterpret_cast<const bf16x8*>(lb + 16384 + off);
        bl[fb] = *reinterpret_cast<const bf16x8*>(lb + 24576 + off);
      }
      asm volatile("s_waitcnt lgkmcnt(0)" ::: "memory");
      __builtin_amdgcn_sched_barrier(0);
      __builtin_amdgcn_s_setprio(1);
      #pragma unroll
      for (int fa = 0; fa < 4; ++fa)
        #pragma unroll
        for (int fb = 0; fb < 2; ++fb) {
          acc[fa][fb] = __builtin_amdgcn_mfma_f32_16x16x32_bf16(ah[fa], bh[fb], acc[fa][fb], 0, 0, 0);
          acc[fa][fb] = __builtin_amdgcn_mfma_f32_16x16x32_bf16(ah[fa], bl[fb], acc[fa][fb], 0, 0, 0);
          acc[fa][fb] = __builtin_amdgcn_mfma_f32_16x16x32_bf16(al[fa], bh[fb], acc[fa][fb], 0, 0, 0);
        }
      __builtin_amdgcn_s_setprio(0);
    }
    __builtin_amdgcn_s_barrier();             // buffer consumed; reusable
  }

  // ---- epilogue: NT-Xent online merge per output row ----
  const int ndup = min(dupcnt[0], DCAP);
  int ljv[2]; float qjv[2]; int fjv[2]; int gjv[2];
  #pragma unroll
  for (int fb = 0; fb < 2; ++fb) {
    const int gj = j0 + wc * 32 + fb * 16 + c0;
    const int lab = labels[gj];
    ljv[fb] = (msk[gj] == 1 && lab >= 0) ? lab : -1;
    qjv[fb] = qv[gj];
    fjv[fb] = rowflag[gj];
    gjv[fb] = gj;
  }
  #pragma unroll
  for (int fa = 0; fa < 4; ++fa) {
    const int ibase = i0 + wr * 64 + fa * 16 + gq * 4;
    int li4[4], mi4[4], fi4[4]; float qi4[4];
    *reinterpret_cast<int4*>(li4)   = *reinterpret_cast<const int4*>(labels + ibase);
    *reinterpret_cast<int4*>(mi4)   = *reinterpret_cast<const int4*>(msk + ibase);
    *reinterpret_cast<int4*>(fi4)   = *reinterpret_cast<const int4*>(rowflag + ibase);
    *reinterpret_cast<float4*>(qi4) = *reinterpret_cast<const float4*>(qv + ibase);
    #pragma unroll
    for (int r = 0; r < 4; ++r) {
      const int gi = ibase + r;
      const int li = (mi4[r] == 1 && li4[r] >= 0) ? li4[r] : -1;
      float m = -INFINITY, n = 0.f, d = 0.f, c = 0.f;
      if (li >= 0) {
        #pragma unroll
        for (int fb = 0; fb < 2; ++fb) {
          const int lj = ljv[fb];
          bool inc = (lj >= 0) && (gi != gjv[fb]);
          if (inc && fi4[r] && fjv[fb]) {
            int plo = min(gi, gjv[fb]), phi = max(gi, gjv[fb]);
            for (int e = 0; e < ndup; ++e) {
              int2 p = duplist[e];
              if (p.x == plo && p.y == phi) { inc = false; break; }
            }
          }
          if (inc) {
            float S = acc[fa][fb][r];
            float l = 64.0f - 0.25f * (qi4[r] + qjv[fb] + S);
            float w = (li == lj) ? 1.0f : 0.0f;
            mergeState(m, n, d, l, w, 1.0f);
            c += w;
          }
        }
      }
      #pragma unroll
      for (int o = 1; o < 16; o <<= 1) {
        float m2 = __shfl_xor(m, o);
        float n2 = __shfl_xor(n, o);
        float d2 = __shfl_xor(d, o);
        float c2 = __shfl_xor(c, o);
        mergeState(m, n, d, m2, n2, d2);
        c += c2;
      }
      if (c0 == 0)
        partials[(size_t)(bj * 4 + wc) * NROWS + gi] = make_float4(m, n, d, c);
    }
  }
}

// ---------------------------------------------------------------------------
// K3a: merge 64 j-slices per row, per-block partial sums (no atomics).
// ---------------------------------------------------------------------------
__global__ __launch_bounds__(256) void k3a(const float4* __restrict__ partials,
                                           float2* __restrict__ bsums)
{
  const int r = blockIdx.x * 256 + threadIdx.x;
  float m = -INFINITY, n = 0.f, d = 0.f, c = 0.f;
  #pragma unroll 8
  for (int js = 0; js < NJS; ++js) {
    float4 p = partials[(size_t)js * NROWS + r];
    mergeState(m, n, d, p.x, p.y, p.z);
    c += p.w;
  }
  float lf = 0.f, ns = 0.f;
  if (c > 0.f) {
    lf = log2f(d) - log2f(n) + log2f(c);
    ns = 1.f;
  }
  #pragma unroll
  for (int o = 32; o; o >>= 1) {
    lf += __shfl_down(lf, o);
    ns += __shfl_down(ns, o);
  }
  __shared__ float sl[4], sn[4];
  const int wid = threadIdx.x >> 6;
  if ((threadIdx.x & 63) == 0) { sl[wid] = lf; sn[wid] = ns; }
  __syncthreads();
  if (threadIdx.x == 0)
    bsums[blockIdx.x] = make_float2(sl[0] + sl[1] + sl[2] + sl[3],
                                    sn[0] + sn[1] + sn[2] + sn[3]);
}

__global__ __launch_bounds__(64) void k3b(const float2* __restrict__ bsums,
                                          float* __restrict__ out)
{
  if (threadIdx.x == 0) {
    float L = 0.f, C = 0.f;
    for (int b = 0; b < 8; ++b) { L += bsums[b].x; C += bsums[b].y; }
    out[0] = L / fmaxf(C, 1.0f);
  }
}

// ---------------------------------------------------------------------------
extern "C" void kernel_launch(void* const* d_in, const int* in_sizes, int n_in,
                              void* d_out, int out_size, void* d_ws, size_t ws_size,
                              hipStream_t stream) {
  const float* E   = (const float*)d_in[0];
  const int*   tid = (const int*)d_in[1];
  const int*   msk = (const int*)d_in[2];
  const float* Wmu = (const float*)d_in[3];
  const float* bmu = (const float*)d_in[4];
  const float* Wsg = (const float*)d_in[5];
  const float* bsg = (const float*)d_in[6];

  unsigned char* w = (unsigned char*)d_ws;
  unsigned short* Ehi  = (unsigned short*)w;  w += (size_t)NROWS * HDIM * 2;   // 3 MB
  unsigned short* Elo  = (unsigned short*)w;  w += (size_t)NROWS * HDIM * 2;   // 3 MB
  unsigned short* Wthi = (unsigned short*)w;  w += (size_t)256 * HDIM * 2;     // 384 KB
  unsigned short* Wtlo = (unsigned short*)w;  w += (size_t)256 * HDIM * 2;     // 384 KB
  unsigned short* Fhi  = (unsigned short*)w;  w += (size_t)NROWS * FEAT * 2;   // 2 MB
  unsigned short* Flo  = (unsigned short*)w;  w += (size_t)NROWS * FEAT * 2;   // 2 MB
  float* Cpart         = (float*)w;           w += (size_t)4 * NROWS * 256 * 4; // 8 MB
  float* qv            = (float*)w;           w += (size_t)NROWS * 4;
  unsigned long long* tab = (unsigned long long*)w; w += (size_t)TSLOTS * 8;   // 64 KB
  int* rowflag         = (int*)w;             w += (size_t)NROWS * 4;
  int* dupcnt          = (int*)w;             w += 256;
  float2* bsums        = (float2*)w;          w += 256;
  int2* duplist        = (int2*)w;            w += (size_t)DCAP * 8;
  float4* partials     = (float4*)w;          w += (size_t)NJS * NROWS * 16;   // 2 MB

  k0_prep<<<873, 256, 0, stream>>>(E, Wmu, Wsg, Ehi, Elo, Wthi, Wtlo,
                                   tab, rowflag, dupcnt);
  k1m<<<256, 256, 0, stream>>>(Ehi, Elo, Wthi, Wtlo, Cpart);
  k1e<<<512, 256, 0, stream>>>(Cpart, bmu, bsg, Fhi, Flo, qv,
                               tab, rowflag, dupcnt, duplist);
  k2_mfma<<<256, 512, 0, stream>>>(Fhi, Flo, qv, tid, msk, rowflag,
                                   dupcnt, duplist, partials);
  k3a<<<8, 256, 0, stream>>>(partials, bsums);
  k3b<<<1, 64, 0, stream>>>(bsums, (float*)d_out);
}

// Round 9
// 56.850 us; speedup vs baseline: 1.7318x; 1.0484x over previous
//
#include <hip/hip_runtime.h>
#include <math.h>

#define NROWS 2048
#define HDIM 768
#define DDIM 128
#define FEAT 512
#define FCAT 1024
#define DCAP 2048
#define TSLOTS 8192
#define NJS 64

typedef __attribute__((ext_vector_type(8))) short bf16x8;
typedef __attribute__((ext_vector_type(4))) float f32x4;

// Online logsumexp-style merge: state (m, n, d) <- merge with (m2, n2, d2).
__device__ __forceinline__ void mergeState(float& m, float& n, float& d,
                                           float m2, float n2, float d2) {
  float M = fmaxf(m, m2);
  float s1 = (m >= M) ? 1.0f : __expf(m - M);
  float s2 = (m2 >= M) ? 1.0f : __expf(m2 - M);
  n = n * s1 + n2 * s2;
  d = d * s1 + d2 * s2;
  m = M;
}

__device__ __forceinline__ unsigned short bfhi(float x) {
  unsigned int u = __float_as_uint(x);
  return (unsigned short)((u + 0x7fffu + ((u >> 16) & 1u)) >> 16);
}
__device__ __forceinline__ float bf2f(unsigned short h) {
  return __uint_as_float(((unsigned int)h) << 16);
}

__device__ __forceinline__ void gload16(const void* g, void* l) {
  __builtin_amdgcn_global_load_lds(
      (const __attribute__((address_space(1))) void*)g,
      (__attribute__((address_space(3))) void*)l, 16, 0, 0);
}

// ---------------------------------------------------------------------------
// k0_prep: (a) Ehi/Elo = bf16-split of relu(E); (b) Wthi/Wtlo = bf16-split of
// [Wmu|Wsg] transposed to [256 cols][768 k]; (c) clear hash table/flags.
// ---------------------------------------------------------------------------
__global__ __launch_bounds__(256) void k0_prep(
    const float* __restrict__ E, const float* __restrict__ Wmu,
    const float* __restrict__ Wsg,
    unsigned short* __restrict__ Ehi, unsigned short* __restrict__ Elo,
    unsigned short* __restrict__ Wthi, unsigned short* __restrict__ Wtlo,
    unsigned long long* __restrict__ tab, int* __restrict__ rowflag,
    int* __restrict__ dupcnt)
{
  const int bid = blockIdx.x, t = threadIdx.x;
  if (bid < 768) {
    const int base = bid * 2048 + t * 8;
    float4 v0 = *reinterpret_cast<const float4*>(E + base);
    float4 v1 = *reinterpret_cast<const float4*>(E + base + 4);
    const float v[8] = {v0.x, v0.y, v0.z, v0.w, v1.x, v1.y, v1.z, v1.w};
    unsigned short h[8], l[8];
    #pragma unroll
    for (int i = 0; i < 8; ++i) {
      float f = fmaxf(v[i], 0.f);
      h[i] = bfhi(f);
      l[i] = bfhi(f - bf2f(h[i]));
    }
    *reinterpret_cast<ushort4*>(Ehi + base)     = make_ushort4(h[0], h[1], h[2], h[3]);
    *reinterpret_cast<ushort4*>(Ehi + base + 4) = make_ushort4(h[4], h[5], h[6], h[7]);
    *reinterpret_cast<ushort4*>(Elo + base)     = make_ushort4(l[0], l[1], l[2], l[3]);
    *reinterpret_cast<ushort4*>(Elo + base + 4) = make_ushort4(l[4], l[5], l[6], l[7]);
  } else if (bid < 864) {
    const int tid = (bid - 768) * 256 + t;          // 0..24575
    const int c = tid / 96, kc = (tid % 96) * 8;
    unsigned short h[8], l[8];
    #pragma unroll
    for (int j = 0; j < 8; ++j) {
      float w = (c < 128) ? Wmu[(size_t)(kc + j) * DDIM + c]
                          : Wsg[(size_t)(kc + j) * DDIM + (c - 128)];
      h[j] = bfhi(w);
      l[j] = bfhi(w - bf2f(h[j]));
    }
    const size_t o = (size_t)c * HDIM + kc;
    *reinterpret_cast<ushort4*>(Wthi + o)     = make_ushort4(h[0], h[1], h[2], h[3]);
    *reinterpret_cast<ushort4*>(Wthi + o + 4) = make_ushort4(h[4], h[5], h[6], h[7]);
    *reinterpret_cast<ushort4*>(Wtlo + o)     = make_ushort4(l[0], l[1], l[2], l[3]);
    *reinterpret_cast<ushort4*>(Wtlo + o + 4) = make_ushort4(l[4], l[5], l[6], l[7]);
  } else if (bid < 872) {
    const int i4 = (bid - 864) * 1024 + t * 4;
    #pragma unroll
    for (int k = 0; k < 4; ++k) tab[i4 + k] = 0ULL;
    rowflag[(bid - 864) * 256 + t] = 0;
  } else {
    if (t == 0) dupcnt[0] = 0;
  }
}

// ---------------------------------------------------------------------------
// k1m: split-K MFMA projection GEMM. C[2048][256] partials over 4 K-splits.
// ---------------------------------------------------------------------------
__global__ __launch_bounds__(256) void k1m(
    const unsigned short* __restrict__ Ehi, const unsigned short* __restrict__ Elo,
    const unsigned short* __restrict__ Wthi, const unsigned short* __restrict__ Wtlo,
    float* __restrict__ Cpart)
{
  __shared__ unsigned short lds[24576];   // 48 KB = 2 buf x 12288
  const int t = threadIdx.x;
  const int bid = blockIdx.x;
  const int mt = bid & 31, nt = (bid >> 5) & 1, ks = bid >> 6;
  const int i0 = mt * 64, n0 = nt * 128, kbase = ks * 192;

  const unsigned short* gF[6];
  size_t goff[6];
  int lpb[6];
  #pragma unroll
  for (int rr = 0; rr < 6; ++rr) {
    if (rr < 2) {
      const int s = t, gq = s >> 6, row = s & 63;
      gF[rr] = rr ? Elo : Ehi;
      goff[rr] = (size_t)(i0 + row) * HDIM + kbase + gq * 8;
      lpb[rr] = rr * 2048 + (s & ~63) * 8;
    } else {
      const int s = (rr & 1) * 256 + t, gq = s >> 7, row = s & 127;
      gF[rr] = (rr >= 4) ? Wtlo : Wthi;
      goff[rr] = (size_t)(n0 + row) * HDIM + kbase + gq * 8;
      lpb[rr] = (rr >= 4 ? 8192 : 4096) + (s & ~63) * 8;
    }
  }

  f32x4 acc[2][4];
  #pragma unroll
  for (int a = 0; a < 2; ++a)
    #pragma unroll
    for (int b = 0; b < 4; ++b) {
      acc[a][b][0] = 0.f; acc[a][b][1] = 0.f; acc[a][b][2] = 0.f; acc[a][b][3] = 0.f;
    }

  const int wid = t >> 6, lane = t & 63;
  const int wr = wid >> 1, wc = wid & 1;
  const int gq = lane >> 4, c0 = lane & 15;

  auto stage = [&](int it, int buf) {
    unsigned short* lb = lds + buf * 12288;
    #pragma unroll
    for (int rr = 0; rr < 6; ++rr)
      gload16(gF[rr] + goff[rr] + it * 32, lb + lpb[rr]);
  };

  stage(0, 0);
  __syncthreads();

  for (int it = 0; it < 6; ++it) {
    if (it < 5) {
      stage(it + 1, (it + 1) & 1);
      asm volatile("s_waitcnt vmcnt(6)" ::: "memory");
    } else {
      asm volatile("s_waitcnt vmcnt(0)" ::: "memory");
    }
    __builtin_amdgcn_s_barrier();
    {
      const unsigned short* lb = lds + (it & 1) * 12288;
      bf16x8 ah[2], al[2], bh[4], bl[4];
      #pragma unroll
      for (int fa = 0; fa < 2; ++fa) {
        const int ia = gq * 512 + (wr * 32 + fa * 16 + c0) * 8;
        ah[fa] = *reinterpret_cast<const bf16x8*>(lb + ia);
        al[fa] = *reinterpret_cast<const bf16x8*>(lb + 2048 + ia);
      }
      #pragma unroll
      for (int fb = 0; fb < 4; ++fb) {
        const int ib = gq * 1024 + (wc * 64 + fb * 16 + c0) * 8;
        bh[fb] = *reinterpret_cast<const bf16x8*>(lb + 4096 + ib);
        bl[fb] = *reinterpret_cast<const bf16x8*>(lb + 8192 + ib);
      }
      #pragma unroll
      for (int fa = 0; fa < 2; ++fa)
        #pragma unroll
        for (int fb = 0; fb < 4; ++fb) {
          acc[fa][fb] = __builtin_amdgcn_mfma_f32_16x16x32_bf16(ah[fa], bh[fb], acc[fa][fb], 0, 0, 0);
          acc[fa][fb] = __builtin_amdgcn_mfma_f32_16x16x32_bf16(ah[fa], bl[fb], acc[fa][fb], 0, 0, 0);
          acc[fa][fb] = __builtin_amdgcn_mfma_f32_16x16x32_bf16(al[fa], bh[fb], acc[fa][fb], 0, 0, 0);
        }
    }
    __builtin_amdgcn_s_barrier();
  }

  #pragma unroll
  for (int fa = 0; fa < 2; ++fa)
    #pragma unroll
    for (int fb = 0; fb < 4; ++fb)
      #pragma unroll
      for (int r = 0; r < 4; ++r) {
        const int row = i0 + wr * 32 + fa * 16 + gq * 4 + r;
        const int col = n0 + wc * 64 + fb * 16 + c0;
        Cpart[((size_t)ks * NROWS + row) * 256 + col] = acc[fa][fb][r];
      }
}

// ---------------------------------------------------------------------------
// k1e: reduce 4 K-split partials -> mu/sigma -> Fcat = [hi(512)|lo(512)]
// features, q, and full-mu-vector duplicate hash. Block = 4 rows.
// ---------------------------------------------------------------------------
__global__ __launch_bounds__(256) void k1e(
    const float* __restrict__ Cpart, const float* __restrict__ bmu,
    const float* __restrict__ bsg,
    unsigned short* __restrict__ Fcat,
    float* __restrict__ qout, unsigned long long* __restrict__ tab,
    int* __restrict__ rowflag, int* __restrict__ dupcnt,
    int2* __restrict__ duplist)
{
  __shared__ float sigL[4][DDIM];
  const int t = threadIdx.x;
  const int row = t >> 6, cg = t & 63, c4 = cg * 4;
  const int mat = c4 >> 7, colm = c4 & 127;
  const int rg = blockIdx.x * 4 + row;

  float v[4];
  {
    float4 s0 = *reinterpret_cast<const float4*>(&Cpart[((size_t)0 * NROWS + rg) * 256 + c4]);
    float4 s1 = *reinterpret_cast<const float4*>(&Cpart[((size_t)1 * NROWS + rg) * 256 + c4]);
    float4 s2 = *reinterpret_cast<const float4*>(&Cpart[((size_t)2 * NROWS + rg) * 256 + c4]);
    float4 s3 = *reinterpret_cast<const float4*>(&Cpart[((size_t)3 * NROWS + rg) * 256 + c4]);
    v[0] = ((s0.x + s1.x) + s2.x) + s3.x;
    v[1] = ((s0.y + s1.y) + s2.y) + s3.y;
    v[2] = ((s0.z + s1.z) + s2.z) + s3.z;
    v[3] = ((s0.w + s1.w) + s2.w) + s3.w;
  }

  if (mat == 1) {
    #pragma unroll
    for (int c = 0; c < 4; ++c) {
      float z = v[c] + bsg[colm + c];
      float s = (z > 0.f ? z + 1.0f : __expf(z)) + 1e-14f;
      sigL[row][colm + c] = s;
    }
  }
  __syncthreads();

  float q = 0.f;
  unsigned int hx = 0u, hs = 0u;
  if (mat == 0) {
    float f1[4], f2[4], f3[4], f4[4];
    #pragma unroll
    for (int c = 0; c < 4; ++c) {
      float mu = v[c] + bmu[colm + c];
      float s  = sigL[row][colm + c];
      float inv = 1.0f / s;
      f1[c] = inv;
      f2[c] = s + mu * mu;
      f3[c] = -2.0f * mu * inv;
      f4[c] = mu;
      q += mu * mu * inv;
      unsigned int b = __float_as_uint(mu);
      if (b == 0x80000000u) b = 0u;
      unsigned int hm = (b ^ ((unsigned int)(colm + c) * 0x9E3779B9u)) * 0x85EBCA6Bu;
      hm ^= hm >> 13;
      hx ^= hm;
      hs += hm * 0xC2B2AE35u;
    }
    const float* blocks[4] = {f1, f2, f3, f4};
    #pragma unroll
    for (int b = 0; b < 4; ++b) {
      const float* vv = blocks[b];
      unsigned short h[4], l[4];
      #pragma unroll
      for (int c = 0; c < 4; ++c) {
        h[c] = bfhi(vv[c]);
        l[c] = bfhi(vv[c] - bf2f(h[c]));
      }
      size_t off = (size_t)rg * FCAT + b * 128 + colm;
      *reinterpret_cast<ushort4*>(&Fcat[off])       = make_ushort4(h[0], h[1], h[2], h[3]);
      *reinterpret_cast<ushort4*>(&Fcat[off + 512]) = make_ushort4(l[0], l[1], l[2], l[3]);
    }
  }
  #pragma unroll
  for (int o = 16; o; o >>= 1) q += __shfl_xor(q, o, 32);
  #pragma unroll
  for (int o = 1; o < 32; o <<= 1) {
    hx ^= (unsigned int)__shfl_xor((int)hx, o, 32);
    hs += (unsigned int)__shfl_xor((int)hs, o, 32);
  }
  if (cg == 0) {
    qout[rg] = q;
    unsigned long long key = (((unsigned long long)hx << 32) | hs) & ~0xFFFULL;
    if (key == 0ULL) key = 0x123456789000ULL;
    const unsigned long long me = key | (unsigned long long)(rg + 1);
    unsigned int h = (hx ^ (hs * 0x9E3779B9u)) & (TSLOTS - 1);
    for (;;) {
      unsigned long long old = atomicCAS(&tab[h], 0ULL, me);
      if (old == 0ULL) break;
      if ((old & ~0xFFFULL) == key) {
        int r2 = (int)(old & 0xFFFULL) - 1;
        rowflag[rg] = 1; rowflag[r2] = 1;
        int e = atomicAdd(dupcnt, 1);
        if (e < DCAP) duplist[e] = make_int2(min(rg, r2), max(rg, r2));
      }
      h = (h + 1u) & (TSLOTS - 1);
    }
  }
}

// ---------------------------------------------------------------------------
// K2: concat-K MFMA all-pairs (virtual K=1024 = [hi|lo]) + NT-Xent epilogue.
// k1m geometry: tile 128x64, 256 threads (4 waves 2Mx2N, wave 64x32), K-chunk
// 64 ushorts, dbuf 48 KB -> grid 16x32 = 512 blocks = 2 independent
// blocks/CU (cross-block phase overlap). Counted vmcnt(6), raw barriers,
// setprio. Coalesced line staging with in-line XOR swizzle; conflict-free
// ds_read (slot = (kc*4+gq)^(c0&7)). B feature swap = k^128 (valid per half).
// ---------------------------------------------------------------------------
__global__ __launch_bounds__(256, 2) void k2_mfma(
    const unsigned short* __restrict__ Fcat,
    const float* __restrict__ qv, const int* __restrict__ labels,
    const int* __restrict__ msk, const int* __restrict__ rowflag,
    const int* __restrict__ dupcnt, const int2* __restrict__ duplist,
    float4* __restrict__ partials)
{
  __shared__ unsigned short lds[2 * 12288];   // 48 KB (A 16KB + B 8KB per buf)
  const int t = threadIdx.x;
  // XCD-chunked swizzle: 512 blocks, 8 XCDs x 64 contiguous wg (512%8==0)
  const int orig = blockIdx.x;
  const int wg = (orig & 7) * 64 + (orig >> 3);
  const int bi = wg >> 5, bj = wg & 31;
  const int i0 = bi * 128, j0 = bj * 64;
  const int wid = t >> 6, lane = t & 63;
  const int wr = wid >> 1, wc = wid & 1;      // 2M x 2N waves, wave tile 64x32
  const int gq = lane >> 4, c0 = lane & 15;

  // staging: 6 gload16/thread. slot s = r*256+t; s<1024: A row s>>3;
  // s>=1024: B row (s-1024)>>3. In-row 16B-block (s&7)^(row&7) (same line).
  size_t gaddr[6];
  int lbase[6];
  #pragma unroll
  for (int r = 0; r < 6; ++r) {
    const int s = r * 256 + t;
    const int isB = s >> 10;
    const int si = isB ? (s - 1024) : s;
    const int row = si >> 3;
    const int kb = (si & 7) ^ (row & 7);
    gaddr[r] = (size_t)((isB ? j0 : i0) + row) * FCAT + kb * 8;
    lbase[r] = (r * 256 + (t & ~63)) * 8;     // wave-uniform ushort base
  }

  f32x4 acc[4][2];
  #pragma unroll
  for (int a = 0; a < 4; ++a)
    #pragma unroll
    for (int b = 0; b < 2; ++b) {
      acc[a][b][0] = 0.f; acc[a][b][1] = 0.f; acc[a][b][2] = 0.f; acc[a][b][3] = 0.f;
    }

  auto stage = [&](int c) {
    unsigned short* lb = lds + (c & 1) * 12288;
    const int ka = c * 64;                    // A chunk base (ushorts)
    const int kbb = ka ^ 128;                 // B feature-pair swap
    #pragma unroll
    for (int r = 0; r < 6; ++r)
      gload16(Fcat + gaddr[r] + (r < 4 ? ka : kbb), lb + lbase[r]);
  };

  stage(0);

  #pragma unroll 2
  for (int c = 0; c < 16; ++c) {
    if (c < 15) {
      stage(c + 1);
      asm volatile("s_waitcnt vmcnt(6)" ::: "memory");
    } else {
      asm volatile("s_waitcnt vmcnt(0)" ::: "memory");
    }
    __builtin_amdgcn_s_barrier();             // chunk c fully in LDS
    const unsigned short* lb = lds + (c & 1) * 12288;
    #pragma unroll
    for (int kc = 0; kc < 2; ++kc) {
      const int slot = ((kc * 4 + gq) ^ (c0 & 7)) * 8;
      bf16x8 af[4], bf[2];
      #pragma unroll
      for (int fa = 0; fa < 4; ++fa) {
        const int off = (wr * 64 + fa * 16 + c0) * 64 + slot;
        af[fa] = *reinterpret_cast<const bf16x8*>(lb + off);
      }
      #pragma unroll
      for (int fb = 0; fb < 2; ++fb) {
        const int off = 8192 + (wc * 32 + fb * 16 + c0) * 64 + slot;
        bf[fb] = *reinterpret_cast<const bf16x8*>(lb + off);
      }
      asm volatile("s_waitcnt lgkmcnt(0)" ::: "memory");
      __builtin_amdgcn_sched_barrier(0);
      __builtin_amdgcn_s_setprio(1);
      #pragma unroll
      for (int fa = 0; fa < 4; ++fa)
        #pragma unroll
        for (int fb = 0; fb < 2; ++fb)
          acc[fa][fb] = __builtin_amdgcn_mfma_f32_16x16x32_bf16(
              af[fa], bf[fb], acc[fa][fb], 0, 0, 0);
      __builtin_amdgcn_s_setprio(0);
    }
    __builtin_amdgcn_s_barrier();             // buffer consumed; reusable
  }

  // ---- epilogue: NT-Xent online merge per output row ----
  const int ndup = min(dupcnt[0], DCAP);
  int ljv[2]; float qjv[2]; int fjv[2]; int gjv[2];
  #pragma unroll
  for (int fb = 0; fb < 2; ++fb) {
    const int gj = j0 + wc * 32 + fb * 16 + c0;
    const int lab = labels[gj];
    ljv[fb] = (msk[gj] == 1 && lab >= 0) ? lab : -1;
    qjv[fb] = qv[gj];
    fjv[fb] = rowflag[gj];
    gjv[fb] = gj;
  }
  #pragma unroll
  for (int fa = 0; fa < 4; ++fa) {
    const int ibase = i0 + wr * 64 + fa * 16 + gq * 4;
    int li4[4], mi4[4], fi4[4]; float qi4[4];
    *reinterpret_cast<int4*>(li4)   = *reinterpret_cast<const int4*>(labels + ibase);
    *reinterpret_cast<int4*>(mi4)   = *reinterpret_cast<const int4*>(msk + ibase);
    *reinterpret_cast<int4*>(fi4)   = *reinterpret_cast<const int4*>(rowflag + ibase);
    *reinterpret_cast<float4*>(qi4) = *reinterpret_cast<const float4*>(qv + ibase);
    #pragma unroll
    for (int r = 0; r < 4; ++r) {
      const int gi = ibase + r;
      const int li = (mi4[r] == 1 && li4[r] >= 0) ? li4[r] : -1;
      float m = -INFINITY, n = 0.f, d = 0.f, c = 0.f;
      if (li >= 0) {
        #pragma unroll
        for (int fb = 0; fb < 2; ++fb) {
          const int lj = ljv[fb];
          bool inc = (lj >= 0) && (gi != gjv[fb]);
          if (inc && fi4[r] && fjv[fb]) {
            int plo = min(gi, gjv[fb]), phi = max(gi, gjv[fb]);
            for (int e = 0; e < ndup; ++e) {
              int2 p = duplist[e];
              if (p.x == plo && p.y == phi) { inc = false; break; }
            }
          }
          if (inc) {
            float S = acc[fa][fb][r];
            float l = 64.0f - 0.25f * (qi4[r] + qjv[fb] + S);
            float w = (li == lj) ? 1.0f : 0.0f;
            mergeState(m, n, d, l, w, 1.0f);
            c += w;
          }
        }
      }
      #pragma unroll
      for (int o = 1; o < 16; o <<= 1) {
        float m2 = __shfl_xor(m, o);
        float n2 = __shfl_xor(n, o);
        float d2 = __shfl_xor(d, o);
        float c2 = __shfl_xor(c, o);
        mergeState(m, n, d, m2, n2, d2);
        c += c2;
      }
      if (c0 == 0)
        partials[(size_t)(bj * 2 + wc) * NROWS + gi] = make_float4(m, n, d, c);
    }
  }
}

// ---------------------------------------------------------------------------
// K3a: merge 64 j-slices per row, per-block partial sums (no atomics).
// ---------------------------------------------------------------------------
__global__ __launch_bounds__(256) void k3a(const float4* __restrict__ partials,
                                           float2* __restrict__ bsums)
{
  const int r = blockIdx.x * 256 + threadIdx.x;
  float m = -INFINITY, n = 0.f, d = 0.f, c = 0.f;
  #pragma unroll 8
  for (int js = 0; js < NJS; ++js) {
    float4 p = partials[(size_t)js * NROWS + r];
    mergeState(m, n, d, p.x, p.y, p.z);
    c += p.w;
  }
  float lf = 0.f, ns = 0.f;
  if (c > 0.f) {
    lf = log2f(d) - log2f(n) + log2f(c);
    ns = 1.f;
  }
  #pragma unroll
  for (int o = 32; o; o >>= 1) {
    lf += __shfl_down(lf, o);
    ns += __shfl_down(ns, o);
  }
  __shared__ float sl[4], sn[4];
  const int wid = threadIdx.x >> 6;
  if ((threadIdx.x & 63) == 0) { sl[wid] = lf; sn[wid] = ns; }
  __syncthreads();
  if (threadIdx.x == 0)
    bsums[blockIdx.x] = make_float2(sl[0] + sl[1] + sl[2] + sl[3],
                                    sn[0] + sn[1] + sn[2] + sn[3]);
}

__global__ __launch_bounds__(64) void k3b(const float2* __restrict__ bsums,
                                          float* __restrict__ out)
{
  if (threadIdx.x == 0) {
    float L = 0.f, C = 0.f;
    for (int b = 0; b < 8; ++b) { L += bsums[b].x; C += bsums[b].y; }
    out[0] = L / fmaxf(C, 1.0f);
  }
}

// ---------------------------------------------------------------------------
extern "C" void kernel_launch(void* const* d_in, const int* in_sizes, int n_in,
                              void* d_out, int out_size, void* d_ws, size_t ws_size,
                              hipStream_t stream) {
  const float* E   = (const float*)d_in[0];
  const int*   tid = (const int*)d_in[1];
  const int*   msk = (const int*)d_in[2];
  const float* Wmu = (const float*)d_in[3];
  const float* bmu = (const float*)d_in[4];
  const float* Wsg = (const float*)d_in[5];
  const float* bsg = (const float*)d_in[6];

  unsigned char* w = (unsigned char*)d_ws;
  unsigned short* Ehi  = (unsigned short*)w;  w += (size_t)NROWS * HDIM * 2;   // 3 MB
  unsigned short* Elo  = (unsigned short*)w;  w += (size_t)NROWS * HDIM * 2;   // 3 MB
  unsigned short* Wthi = (unsigned short*)w;  w += (size_t)256 * HDIM * 2;     // 384 KB
  unsigned short* Wtlo = (unsigned short*)w;  w += (size_t)256 * HDIM * 2;     // 384 KB
  unsigned short* Fcat = (unsigned short*)w;  w += (size_t)NROWS * FCAT * 2;   // 4 MB
  float* Cpart         = (float*)w;           w += (size_t)4 * NROWS * 256 * 4; // 8 MB
  float* qv            = (float*)w;           w += (size_t)NROWS * 4;
  unsigned long long* tab = (unsigned long long*)w; w += (size_t)TSLOTS * 8;   // 64 KB
  int* rowflag         = (int*)w;             w += (size_t)NROWS * 4;
  int* dupcnt          = (int*)w;             w += 256;
  float2* bsums        = (float2*)w;          w += 256;
  int2* duplist        = (int2*)w;            w += (size_t)DCAP * 8;
  float4* partials     = (float4*)w;          w += (size_t)NJS * NROWS * 16;   // 2 MB

  k0_prep<<<873, 256, 0, stream>>>(E, Wmu, Wsg, Ehi, Elo, Wthi, Wtlo,
                                   tab, rowflag, dupcnt);
  k1m<<<256, 256, 0, stream>>>(Ehi, Elo, Wthi, Wtlo, Cpart);
  k1e<<<512, 256, 0, stream>>>(Cpart, bmu, bsg, Fcat, qv,
                               tab, rowflag, dupcnt, duplist);
  k2_mfma<<<512, 256, 0, stream>>>(Fcat, qv, tid, msk, rowflag,
                                   dupcnt, duplist, partials);
  k3a<<<8, 256, 0, stream>>>(partials, bsums);
  k3b<<<1, 64, 0, stream>>>(bsums, (float*)d_out);
}